// Round 1
// baseline (781.025 us; speedup 1.0000x reference)
//
#include <hip/hip_runtime.h>
#include <math.h>

#define Bn 2
#define Cc 256
#define Hh 64
#define Ww 96
#define Nn (Hh*Ww)                 // 6144
#define Kk 8
#define WINs 9
#define NLEV 5
#define TM 64
#define SCH 4                      // column split
#define CPC (Nn/SCH)               // 1536 cols per chunk
#define NTILES (CPC/64)            // 24

// sorted-descending top-8 insert, all-static indices (stays in VGPRs)
#define TOPK_INSERT(v, ix, VA, IA) do {                                   \
  if ((v) > VA[7]) {                                                      \
    VA[7] = (v); IA[7] = (ix);                                            \
    _Pragma("unroll")                                                     \
    for (int _s = 7; _s > 0; --_s) {                                      \
      if (VA[_s] > VA[_s-1]) {                                            \
        float _tv = VA[_s]; VA[_s] = VA[_s-1]; VA[_s-1] = _tv;            \
        int   _ti = IA[_s]; IA[_s] = IA[_s-1]; IA[_s-1] = _ti;            \
      }                                                                   \
    }                                                                     \
  }                                                                       \
} while (0)

// ---------------------------------------------------------------------------
// Kernel 1: fused fp32 correlation GEMM + per-row top-8 (per column chunk)
// grid = B * (N/TM) * SCH = 768 blocks, 256 threads
// ---------------------------------------------------------------------------
__global__ __launch_bounds__(256, 2) void corr_topk_kernel(
    const float* __restrict__ f1, const float* __restrict__ f2,
    float* __restrict__ pvals, int* __restrict__ pidx)
{
  __shared__ float As[Cc][TM];   // 64 KB: full A tile [c][row]
  __shared__ float Bs[64][64];   // 16 KB: B chunk [c][col]

  const int tid  = threadIdx.x;
  const int bid  = blockIdx.x;
  const int b    = bid / ((Nn/TM)*SCH);
  const int r    = bid % ((Nn/TM)*SCH);
  const int rt   = r >> 2;
  const int sc   = r & 3;
  const int row0 = rt * TM;
  const int col0 = sc * CPC;

  const float* f1b = f1 + (size_t)b*Cc*Nn + row0;
  const float* f2b = f2 + (size_t)b*Cc*Nn + col0;

  // stage A fully: 256x64 floats
  {
    const int rr = (tid & 15) << 2;
    const int cb = tid >> 4;
    #pragma unroll
    for (int it = 0; it < 16; ++it) {
      const int c = cb + it*16;
      *(float4*)(&As[c][rr]) = *(const float4*)(&f1b[(size_t)c*Nn + rr]);
    }
  }

  const int tr = tid >> 4;   // row group 0..15 (4 rows each)
  const int tc = tid & 15;   // col group 0..15 (4 cols each)

  float va[4][8]; int ia[4][8];
  #pragma unroll
  for (int i = 0; i < 4; ++i)
    #pragma unroll
    for (int j = 0; j < 8; ++j) { va[i][j] = -INFINITY; ia[i][j] = 0; }

  for (int ct = 0; ct < NTILES; ++ct) {
    float acc[4][4];
    #pragma unroll
    for (int i = 0; i < 4; ++i)
      #pragma unroll
      for (int j = 0; j < 4; ++j) acc[i][j] = 0.f;

    for (int c0 = 0; c0 < Cc; c0 += 64) {
      __syncthreads();
      { // stage B chunk: 64 c x 64 cols
        const int colr = (tid & 15) << 2;
        const int cb   = tid >> 4;
        #pragma unroll
        for (int it = 0; it < 4; ++it) {
          const int cc = cb + it*16;
          *(float4*)(&Bs[cc][colr]) =
              *(const float4*)(&f2b[(size_t)(c0+cc)*Nn + ct*64 + colr]);
        }
      }
      __syncthreads();
      #pragma unroll 8
      for (int cc = 0; cc < 64; ++cc) {
        const float4 a  = *(const float4*)(&As[c0+cc][tr<<2]);
        const float4 bv = *(const float4*)(&Bs[cc][tc<<2]);
        acc[0][0] += a.x*bv.x; acc[0][1] += a.x*bv.y; acc[0][2] += a.x*bv.z; acc[0][3] += a.x*bv.w;
        acc[1][0] += a.y*bv.x; acc[1][1] += a.y*bv.y; acc[1][2] += a.y*bv.z; acc[1][3] += a.y*bv.w;
        acc[2][0] += a.z*bv.x; acc[2][1] += a.z*bv.y; acc[2][2] += a.z*bv.z; acc[2][3] += a.z*bv.w;
        acc[3][0] += a.w*bv.x; acc[3][1] += a.w*bv.y; acc[3][2] += a.w*bv.z; acc[3][3] += a.w*bv.w;
      }
    }
    // update per-row top-8 with this tile's 4x4 results
    const int colg = col0 + ct*64 + (tc << 2);
    #pragma unroll
    for (int i = 0; i < 4; ++i) {
      #pragma unroll
      for (int j = 0; j < 4; ++j) {
        TOPK_INSERT(acc[i][j], colg + j, va[i], ia[i]);
      }
    }
  }

  // merge 16 column-thread lists per row inside the block (reuse As as scratch)
  __syncthreads();
  float* mv = &As[0][0];                  // 8192 floats
  int*   mi = (int*)(&As[0][0]) + 8192;   // 8192 ints
  #pragma unroll
  for (int i = 0; i < 4; ++i) {
    const int lr = (tr << 2) + i;
    #pragma unroll
    for (int j = 0; j < 8; ++j) {
      mv[lr*128 + (tc<<3) + j] = va[i][j];
      mi[lr*128 + (tc<<3) + j] = ia[i][j];
    }
  }
  __syncthreads();
  if (tid < TM) {
    float tv[8]; int ti[8];
    #pragma unroll
    for (int j = 0; j < 8; ++j) { tv[j] = -INFINITY; ti[j] = 0; }
    for (int e = 0; e < 128; ++e) {
      const int e2 = (e + (tid << 1)) & 127;   // rotate start: break bank conflicts
      const float v = mv[tid*128 + e2];
      const int  ix = mi[tid*128 + e2];
      TOPK_INSERT(v, ix, tv, ti);
    }
    const int g = b*Nn + row0 + tid;
    float* pv = pvals + (size_t)g*(SCH*8) + sc*8;
    int*   pi = pidx  + (size_t)g*(SCH*8) + sc*8;
    #pragma unroll
    for (int j = 0; j < 8; ++j) { pv[j] = tv[j]; pi[j] = ti[j]; }
  }
}

// ---------------------------------------------------------------------------
// Kernel 2: merge partial top-8s -> displacement -> 5-level bilinear scatter
// grid = ((B*N)/128, NLEV), 128 threads; thread-private 81-float LDS strip
// ---------------------------------------------------------------------------
__global__ __launch_bounds__(128) void pyramid_kernel(
    const float* __restrict__ pvals, const int* __restrict__ pidx,
    const float* __restrict__ flow, float* __restrict__ out)
{
  __shared__ float accs[128*81];   // 41,472 B
  const int tid = threadIdx.x;
  const int g   = blockIdx.x*128 + tid;   // b*N + n
  const int lvl = blockIdx.y;
  const int b   = g / Nn;
  const int n   = g % Nn;

  // merge the 4 chunk-local top-8s into the global top-8
  float tv[8]; int ti[8];
  #pragma unroll
  for (int j = 0; j < 8; ++j) { tv[j] = -INFINITY; ti[j] = 0; }
  const float* pv = pvals + (size_t)g*(SCH*8);
  const int*   pi = pidx  + (size_t)g*(SCH*8);
  for (int e = 0; e < SCH*8; ++e) {
    const float v = pv[e]; const int ix = pi[e];
    TOPK_INSERT(v, ix, tv, ti);
  }

  const int y = n / Ww, x = n % Ww;
  const float fly = flow[((size_t)b*2 + 1)*Nn + n];   // flow[:, ::-1] -> ch0 = flow[1]
  const float flx = flow[((size_t)b*2 + 0)*Nn + n];
  const float scale = 1.0f / (float)(1 << lvl);

  float* lacc = &accs[tid*81];
  #pragma unroll
  for (int c2 = 0; c2 < 81; ++c2) lacc[c2] = 0.f;

  #pragma unroll
  for (int k = 0; k < 8; ++k) {
    const int m  = ti[k];
    const int ym = m / Ww, xm = m % Ww;
    const float val = tv[k] * 0.0625f;                 // / sqrt(C)
    const float cy = ((float)(ym - y) - fly) * scale;
    const float cx = ((float)(xm - x) - flx) * scale;
    const float fy0 = floorf(cy), fx0 = floorf(cx);
    const float ry = cy - fy0, rx = cx - fx0;
    const int iy = (int)fy0, ix = (int)fx0;
    // 4 bilinear corners; mask |corner| <= 4 on both dims
    if (iy   >= -4 && iy   <= 4 && ix   >= -4 && ix   <= 4)
      lacc[(iy+4)*9 + (ix+4)]     += (1.f-ry)*(1.f-rx)*val;
    if (iy   >= -4 && iy   <= 4 && ix+1 >= -4 && ix+1 <= 4)
      lacc[(iy+4)*9 + (ix+1+4)]   += (1.f-ry)*rx*val;
    if (iy+1 >= -4 && iy+1 <= 4 && ix   >= -4 && ix   <= 4)
      lacc[(iy+1+4)*9 + (ix+4)]   += ry*(1.f-rx)*val;
    if (iy+1 >= -4 && iy+1 <= 4 && ix+1 >= -4 && ix+1 <= 4)
      lacc[(iy+1+4)*9 + (ix+1+4)] += ry*rx*val;
  }

  // write this level's 81 cells: out[b, lvl*81+cell, y, x]
  const size_t obase = ((size_t)b*(NLEV*81) + lvl*81) * Nn + n;
  #pragma unroll
  for (int c2 = 0; c2 < 81; ++c2)
    out[obase + (size_t)c2*Nn] = lacc[c2];
}

// ---------------------------------------------------------------------------
extern "C" void kernel_launch(void* const* d_in, const int* in_sizes, int n_in,
                              void* d_out, int out_size, void* d_ws, size_t ws_size,
                              hipStream_t stream) {
  const float* fmap1 = (const float*)d_in[0];
  const float* fmap2 = (const float*)d_in[1];
  const float* flow  = (const float*)d_in[2];
  float* out = (float*)d_out;

  // workspace: partial top-8 (vals + idx) per (b, n, chunk): 2 * 1.57 MB
  float* pvals = (float*)d_ws;
  int*   pidx  = (int*)((char*)d_ws + (size_t)Bn*Nn*SCH*8*sizeof(float));

  corr_topk_kernel<<<dim3(Bn*(Nn/TM)*SCH), dim3(256), 0, stream>>>(fmap1, fmap2, pvals, pidx);
  pyramid_kernel<<<dim3((Bn*Nn)/128, NLEV), dim3(128), 0, stream>>>(pvals, pidx, flow, out);
}

// Round 2
// 511.323 us; speedup vs baseline: 1.5275x; 1.5275x over previous
//
#include <hip/hip_runtime.h>
#include <math.h>

#define Bn 2
#define Cc 256
#define Hh 64
#define Ww 96
#define Nn (Hh*Ww)       // 6144
#define NLEV 5
#define SCH 4            // column chunks in MFMA kernel
#define CPC (Nn/SCH)     // 1536 cols per chunk

typedef __bf16 bf16x8 __attribute__((ext_vector_type(8)));
typedef float f32x4v __attribute__((ext_vector_type(4)));

// sorted-descending top-LEN insert, all-static indices (stays in VGPRs)
#define TOPK_INS(v, ix, VA, IA, LEN) do {                                 \
  if ((v) > VA[(LEN)-1]) {                                                \
    VA[(LEN)-1] = (v); IA[(LEN)-1] = (ix);                                \
    _Pragma("unroll")                                                     \
    for (int _s = (LEN)-1; _s > 0; --_s) {                                \
      if (VA[_s] > VA[_s-1]) {                                            \
        float _t = VA[_s]; VA[_s] = VA[_s-1]; VA[_s-1] = _t;              \
        int   _u = IA[_s]; IA[_s] = IA[_s-1]; IA[_s-1] = _u;              \
      }                                                                   \
    }                                                                     \
  }                                                                       \
} while (0)

__device__ inline unsigned short f2bf(float f) {
  __bf16 h = (__bf16)f;
  return __builtin_bit_cast(unsigned short, h);
}

// ---------------------------------------------------------------------------
// Kernel A: [C][N] fp32 -> [N][C] bf16 + [N][C] fp32 (transpose + convert)
// grid = 2 maps * 2 b * 4 ctiles * 96 ntiles = 1536 blocks, 256 threads
// ---------------------------------------------------------------------------
__global__ __launch_bounds__(256) void transpose_convert(
    const float* __restrict__ f1, const float* __restrict__ f2,
    __bf16* __restrict__ t1b, __bf16* __restrict__ t2b,
    float* __restrict__ t1f, float* __restrict__ t2f)
{
  __shared__ float tile[64][65];
  const int tid = threadIdx.x;
  const int bid = blockIdx.x;
  const int map = bid / 768;
  const int rem = bid % 768;
  const int b   = rem / 384;
  const int r2  = rem % 384;
  const int c0  = (r2 / 96) * 64;
  const int n0  = (r2 % 96) * 64;

  const float* src = (map ? f2 : f1) + (size_t)b*Cc*Nn;
  __bf16* dstb = (map ? t2b : t1b) + (size_t)b*Nn*Cc;
  float*  dstf = (map ? t2f : t1f) + (size_t)b*Nn*Cc;

  const int nl = tid & 63;
  const int cb = tid >> 6;
  #pragma unroll
  for (int i = 0; i < 16; ++i) {
    const int c = cb + i*4;
    tile[nl][c] = src[(size_t)(c0 + c)*Nn + n0 + nl];
  }
  __syncthreads();
  #pragma unroll
  for (int j = 0; j < 4; ++j) {
    const int idx = j*256 + tid;
    const int n = idx >> 4, c4 = idx & 15;
    float v0 = tile[n][c4*4+0], v1 = tile[n][c4*4+1];
    float v2 = tile[n][c4*4+2], v3 = tile[n][c4*4+3];
    const size_t obase = (size_t)(n0 + n)*Cc + c0 + c4*4;
    float4 vf = make_float4(v0, v1, v2, v3);
    *(float4*)(dstf + obase) = vf;
    ushort4 ub = make_ushort4(f2bf(v0), f2bf(v1), f2bf(v2), f2bf(v3));
    *(ushort4*)(dstb + obase) = ub;
  }
}

// ---------------------------------------------------------------------------
// Kernel B: bf16 MFMA correlation + per-thread approximate top-8 prefilter.
// grid = 2 b * 96 rowtiles * 4 chunks = 768 blocks, 256 threads (4 waves).
// Block: 64 rows x 1536 cols, K=256. Per col-iter: 256 cols (64/wave).
// LDS: A-tile 32KB swizzled + B-chunk 32KB swizzled (aliased as scan bufs).
// ---------------------------------------------------------------------------
__global__ __launch_bounds__(256) void mfma_prefilter(
    const __bf16* __restrict__ f1t, const __bf16* __restrict__ f2t,
    float* __restrict__ pv, int* __restrict__ pix)
{
  __shared__ __bf16 As[64*256];       // [row][k], granule (k/8) ^ (row&7)
  __shared__ __bf16 Bs[256*64];       // [col][k64], granule ^ ((col>>1)&7)
  float* scanb = (float*)Bs;          // alias: [4 waves][64 rows][32 slots]

  const int tid  = threadIdx.x;
  const int lane = tid & 63;
  const int wv   = tid >> 6;
  const int bid  = blockIdx.x;
  const int b    = bid / 384;
  const int r2   = bid % 384;
  const int row0 = (r2 >> 2) * 64;
  const int sc   = r2 & 3;
  const int col0 = sc * CPC;
  const size_t bN = (size_t)b * Nn;

  // ---- stage A tile (64 rows x 256 K), swizzled granules ----
  #pragma unroll
  for (int i = 0; i < 8; ++i) {
    const int L = i*256 + tid;
    const int row = L >> 5, g = L & 31;
    int4 v = *(const int4*)(f1t + ((bN + row0 + row) << 8) + (g << 3));
    *(int4*)(As + row*256 + ((g ^ (row & 7)) << 3)) = v;
  }

  float tv[8]; int tix[8];
  #pragma unroll
  for (int j = 0; j < 8; ++j) { tv[j] = -INFINITY; tix[j] = 0; }

  const int scanRow = tid & 63;
  const int scanBuf = tid >> 6;

  for (int iter = 0; iter < 6; ++iter) {
    const int cbase = col0 + iter*256;
    f32x4v acc[4][4];
    #pragma unroll
    for (int rg = 0; rg < 4; ++rg)
      #pragma unroll
      for (int cg = 0; cg < 4; ++cg)
        acc[rg][cg] = (f32x4v){0.f, 0.f, 0.f, 0.f};

    int4 st[8];
    // stage chunk 0 to regs
    #pragma unroll
    for (int i = 0; i < 8; ++i) {
      const int L = i*256 + tid;
      const int col = L >> 3, g = L & 7;
      st[i] = *(const int4*)(f2t + ((bN + cbase + col) << 8) + 0*64 + (g << 3));
    }
    __syncthreads();   // scan of prev iter done -> B region free
    #pragma unroll
    for (int i = 0; i < 8; ++i) {
      const int L = i*256 + tid;
      const int col = L >> 3, g = L & 7;
      *(int4*)(Bs + col*64 + ((g ^ ((col >> 1) & 7)) << 3)) = st[i];
    }

    for (int kc = 0; kc < 4; ++kc) {
      if (kc < 3) {
        #pragma unroll
        for (int i = 0; i < 8; ++i) {
          const int L = i*256 + tid;
          const int col = L >> 3, g = L & 7;
          st[i] = *(const int4*)(f2t + ((bN + cbase + col) << 8) + (kc+1)*64 + (g << 3));
        }
      }
      __syncthreads();                 // B writes visible
      #pragma unroll
      for (int ks = 0; ks < 2; ++ks) {
        bf16x8 af[4], bfr[4];
        #pragma unroll
        for (int rg = 0; rg < 4; ++rg) {
          const int row = rg*16 + (lane & 15);
          const int g = kc*8 + ks*4 + (lane >> 4);
          af[rg] = *(const bf16x8*)(As + row*256 + ((g ^ (row & 7)) << 3));
        }
        #pragma unroll
        for (int cg = 0; cg < 4; ++cg) {
          const int cl = wv*64 + cg*16 + (lane & 15);
          const int g = ks*4 + (lane >> 4);
          bfr[cg] = *(const bf16x8*)(Bs + cl*64 + ((g ^ ((cl >> 1) & 7)) << 3));
        }
        #pragma unroll
        for (int rg = 0; rg < 4; ++rg)
          #pragma unroll
          for (int cg = 0; cg < 4; ++cg)
            acc[rg][cg] = __builtin_amdgcn_mfma_f32_16x16x32_bf16(
                af[rg], bfr[cg], acc[rg][cg], 0, 0, 0);
      }
      __syncthreads();                 // all waves done reading Bs
      if (kc < 3) {
        #pragma unroll
        for (int i = 0; i < 8; ++i) {
          const int L = i*256 + tid;
          const int col = L >> 3, g = L & 7;
          *(int4*)(Bs + col*64 + ((g ^ ((col >> 1) & 7)) << 3)) = st[i];
        }
      }
    }

    // ---- dump + scan (2 halves of 32 cols), scan bufs alias Bs ----
    #pragma unroll
    for (int h = 0; h < 2; ++h) {
      float* mybuf = scanb + wv*2048;
      #pragma unroll
      for (int cgh = 0; cgh < 2; ++cgh) {
        const int cg = h*2 + cgh;
        const int cl = cgh*16 + (lane & 15);   // local col 0..31
        #pragma unroll
        for (int rg = 0; rg < 4; ++rg) {
          const int rbase = rg*16 + ((lane >> 4) << 2);
          #pragma unroll
          for (int j = 0; j < 4; ++j) {
            const int rr = rbase + j;
            const int cp = ((((cl >> 2) ^ (rr & 7)) << 2) | (cl & 3));
            mybuf[rr*32 + cp] = acc[rg][cg][j];
          }
        }
      }
      __syncthreads();
      {
        const float* sb = scanb + scanBuf*2048 + scanRow*32;
        const int gc0 = cbase + scanBuf*64 + h*32;
        #pragma unroll
        for (int q = 0; q < 8; ++q) {
          const int pg = q ^ (scanRow & 7);
          f32x4v v4 = *(const f32x4v*)(sb + pg*4);
          #pragma unroll
          for (int e = 0; e < 4; ++e)
            TOPK_INS(v4[e], gc0 + q*4 + e, tv, tix, 8);
        }
      }
      __syncthreads();
    }
  }

  // write partial candidates: per n, 128 slots = 4 chunks * (4 bufs * 8)
  {
    const size_t base = (bN + row0 + scanRow)*128 + sc*32 + scanBuf*8;
    #pragma unroll
    for (int j = 0; j < 8; ++j) { pv[base + j] = tv[j]; pix[base + j] = tix[j]; }
  }
}

// ---------------------------------------------------------------------------
// Kernel C: merge 128 approx candidates -> top-16 -> exact fp32 rescore ->
// exact top-8 per pixel. grid = 192 blocks (64 n each), 256 threads.
// ---------------------------------------------------------------------------
__global__ __launch_bounds__(256) void rescore_select(
    const float* __restrict__ pv, const int* __restrict__ pix,
    const float* __restrict__ t1f, const float* __restrict__ t2f,
    float* __restrict__ fv, int* __restrict__ fi)
{
  __shared__ float cvv[64][48];
  __shared__ int   cii[64][48];
  __shared__ int   cidx[64][16];
  __shared__ float cex[64][16];

  const int tid = threadIdx.x;
  const int bid = blockIdx.x;
  const int b   = bid / 96;
  const int n0  = (bid % 96) * 64;
  const size_t bn0 = (size_t)b*Nn + n0;

  // phase 1: 4 threads per n, each scans 32 approx cands -> top-12
  {
    const int nl = tid & 63, part = tid >> 6;
    const size_t base = (bn0 + nl)*128 + part*32;
    float va[12]; int ia[12];
    #pragma unroll
    for (int j = 0; j < 12; ++j) { va[j] = -INFINITY; ia[j] = 0; }
    for (int j = 0; j < 32; ++j)
      TOPK_INS(pv[base + j], pix[base + j], va, ia, 12);
    #pragma unroll
    for (int j = 0; j < 12; ++j) { cvv[nl][part*12+j] = va[j]; cii[nl][part*12+j] = ia[j]; }
  }
  __syncthreads();

  // phase 1b: one thread per n: approx top-16 of 48
  if (tid < 64) {
    float va[16]; int ia[16];
    #pragma unroll
    for (int j = 0; j < 16; ++j) { va[j] = -INFINITY; ia[j] = 0; }
    for (int e = 0; e < 48; ++e)
      TOPK_INS(cvv[tid][e], cii[tid][e], va, ia, 16);
    #pragma unroll
    for (int j = 0; j < 16; ++j) cidx[tid][j] = ia[j];
  }
  __syncthreads();

  // phase 2: exact fp32 rescore: wave per 16 n, 4 lanes per candidate
  {
    const int w = tid >> 6, lane = tid & 63;
    const int cg = lane >> 2, li = lane & 3;
    for (int s = 0; s < 16; ++s) {
      const int nl = w*16 + s;
      const int m = cidx[nl][cg];
      const float4* p1 = (const float4*)(t1f + (bn0 + nl)*256 + li*64);
      const float4* p2 = (const float4*)(t2f + ((size_t)b*Nn + m)*256 + li*64);
      float sum = 0.f;
      #pragma unroll
      for (int j = 0; j < 16; ++j) {
        float4 a = p1[j], c = p2[j];
        sum += a.x*c.x + a.y*c.y + a.z*c.z + a.w*c.w;
      }
      sum += __shfl_xor(sum, 1);
      sum += __shfl_xor(sum, 2);
      if (li == 0) cex[nl][cg] = sum;
    }
  }
  __syncthreads();

  // phase 3: exact top-8 of 16, write final
  if (tid < 64) {
    float va[8]; int ia[8];
    #pragma unroll
    for (int j = 0; j < 8; ++j) { va[j] = -INFINITY; ia[j] = 0; }
    #pragma unroll
    for (int e = 0; e < 16; ++e)
      TOPK_INS(cex[tid][e], cidx[tid][e], va, ia, 8);
    const size_t base = (bn0 + tid)*8;
    #pragma unroll
    for (int j = 0; j < 8; ++j) { fv[base+j] = va[j]; fi[base+j] = ia[j]; }
  }
}

// ---------------------------------------------------------------------------
// Kernel D: displacement -> 5-level bilinear scatter (unchanged logic)
// grid = ((B*N)/128, NLEV), 128 threads
// ---------------------------------------------------------------------------
__global__ __launch_bounds__(128) void pyramid_kernel(
    const float* __restrict__ fv, const int* __restrict__ fi,
    const float* __restrict__ flow, float* __restrict__ out)
{
  __shared__ float accs[128*81];
  const int tid = threadIdx.x;
  const int g   = blockIdx.x*128 + tid;   // b*N + n
  const int lvl = blockIdx.y;
  const int b   = g / Nn;
  const int n   = g % Nn;

  float tvv[8]; int ti[8];
  #pragma unroll
  for (int k = 0; k < 8; ++k) { tvv[k] = fv[(size_t)g*8 + k]; ti[k] = fi[(size_t)g*8 + k]; }

  const int y = n / Ww, x = n % Ww;
  const float fly = flow[((size_t)b*2 + 1)*Nn + n];
  const float flx = flow[((size_t)b*2 + 0)*Nn + n];
  const float scale = 1.0f / (float)(1 << lvl);

  float* lacc = &accs[tid*81];
  #pragma unroll
  for (int c2 = 0; c2 < 81; ++c2) lacc[c2] = 0.f;

  #pragma unroll
  for (int k = 0; k < 8; ++k) {
    const int m  = ti[k];
    const int ym = m / Ww, xm = m % Ww;
    const float val = tvv[k] * 0.0625f;
    const float cy = ((float)(ym - y) - fly) * scale;
    const float cx = ((float)(xm - x) - flx) * scale;
    const float fy0 = floorf(cy), fx0 = floorf(cx);
    const float ry = cy - fy0, rx = cx - fx0;
    const int iy = (int)fy0, ix = (int)fx0;
    if (iy   >= -4 && iy   <= 4 && ix   >= -4 && ix   <= 4)
      lacc[(iy+4)*9 + (ix+4)]     += (1.f-ry)*(1.f-rx)*val;
    if (iy   >= -4 && iy   <= 4 && ix+1 >= -4 && ix+1 <= 4)
      lacc[(iy+4)*9 + (ix+1+4)]   += (1.f-ry)*rx*val;
    if (iy+1 >= -4 && iy+1 <= 4 && ix   >= -4 && ix   <= 4)
      lacc[(iy+1+4)*9 + (ix+4)]   += ry*(1.f-rx)*val;
    if (iy+1 >= -4 && iy+1 <= 4 && ix+1 >= -4 && ix+1 <= 4)
      lacc[(iy+1+4)*9 + (ix+1+4)] += ry*rx*val;
  }

  const size_t obase = ((size_t)b*(NLEV*81) + lvl*81) * Nn + n;
  #pragma unroll
  for (int c2 = 0; c2 < 81; ++c2)
    out[obase + (size_t)c2*Nn] = lacc[c2];
}

// ---------------------------------------------------------------------------
extern "C" void kernel_launch(void* const* d_in, const int* in_sizes, int n_in,
                              void* d_out, int out_size, void* d_ws, size_t ws_size,
                              hipStream_t stream) {
  const float* fmap1 = (const float*)d_in[0];
  const float* fmap2 = (const float*)d_in[1];
  const float* flow  = (const float*)d_in[2];
  float* out = (float*)d_out;

  char* w = (char*)d_ws;
  const size_t szBf  = (size_t)Bn*Nn*Cc*sizeof(unsigned short); // 6.29 MB
  const size_t szF   = (size_t)Bn*Nn*Cc*sizeof(float);          // 12.58 MB
  const size_t szPv  = (size_t)Bn*Nn*128*sizeof(float);         // 6.29 MB
  const size_t szFv  = (size_t)Bn*Nn*8*sizeof(float);           // 0.39 MB

  __bf16* t1b = (__bf16*)(w);
  __bf16* t2b = (__bf16*)(w + szBf);
  float*  t1f = (float*)(w + 2*szBf);
  float*  t2f = (float*)(w + 2*szBf + szF);
  float*  pv  = (float*)(w + 2*szBf + 2*szF);
  int*    pix = (int*)  (w + 2*szBf + 2*szF + szPv);
  float*  fv  = (float*)(w + 2*szBf + 2*szF + 2*szPv);
  int*    fi  = (int*)  (w + 2*szBf + 2*szF + 2*szPv + szFv);

  transpose_convert<<<dim3(1536), dim3(256), 0, stream>>>(fmap1, fmap2, t1b, t2b, t1f, t2f);
  mfma_prefilter  <<<dim3(768),  dim3(256), 0, stream>>>(t1b, t2b, pv, pix);
  rescore_select  <<<dim3(192),  dim3(256), 0, stream>>>(pv, pix, t1f, t2f, fv, fi);
  pyramid_kernel  <<<dim3(96, NLEV), dim3(128), 0, stream>>>(fv, fi, flow, out);
}

// Round 4
// 387.254 us; speedup vs baseline: 2.0168x; 1.3204x over previous
//
#include <hip/hip_runtime.h>
#include <math.h>

#define Bn 2
#define Cc 256
#define Hh 64
#define Ww 96
#define Nn (Hh*Ww)       // 6144
#define NLEV 5
#define SCH 4            // column chunks (blocks) per row-tile
#define CPC (Nn/SCH)     // 1536 cols per block
#define NITER (CPC/256)  // 6 col-iterations of 256 cols

typedef __bf16 bf16x8 __attribute__((ext_vector_type(8)));
typedef float f32x4v __attribute__((ext_vector_type(4)));

// sorted-descending top-LEN insert, all-static indices (stays in VGPRs)
#define TOPK_INS(v, ix, VA, IA, LEN) do {                                 \
  if ((v) > VA[(LEN)-1]) {                                                \
    VA[(LEN)-1] = (v); IA[(LEN)-1] = (ix);                                \
    _Pragma("unroll")                                                     \
    for (int _s = (LEN)-1; _s > 0; --_s) {                                \
      if (VA[_s] > VA[_s-1]) {                                            \
        float _t = VA[_s]; VA[_s] = VA[_s-1]; VA[_s-1] = _t;              \
        int   _u = IA[_s]; IA[_s] = IA[_s-1]; IA[_s-1] = _u;              \
      }                                                                   \
    }                                                                     \
  }                                                                       \
} while (0)

__device__ __forceinline__ void gld16(const void* g, void* l) {
  __builtin_amdgcn_global_load_lds(
      (const __attribute__((address_space(1))) void*)g,
      (__attribute__((address_space(3))) void*)l, 16, 0, 0);
}

__device__ inline unsigned short f2bf(float f) {
  __bf16 h = (__bf16)f;
  return __builtin_bit_cast(unsigned short, h);
}

// ---------------------------------------------------------------------------
// Kernel A: [C][N] fp32 -> [N][C] bf16 + [N][C] fp32 (transpose + convert)
// ---------------------------------------------------------------------------
__global__ __launch_bounds__(256) void transpose_convert(
    const float* __restrict__ f1, const float* __restrict__ f2,
    __bf16* __restrict__ t1b, __bf16* __restrict__ t2b,
    float* __restrict__ t1f, float* __restrict__ t2f)
{
  __shared__ float tile[64][65];
  const int tid = threadIdx.x;
  const int bid = blockIdx.x;
  const int map = bid / 768;
  const int rem = bid % 768;
  const int b   = rem / 384;
  const int r2  = rem % 384;
  const int c0  = (r2 / 96) * 64;
  const int n0  = (r2 % 96) * 64;

  const float* src = (map ? f2 : f1) + (size_t)b*Cc*Nn;
  __bf16* dstb = (map ? t2b : t1b) + (size_t)b*Nn*Cc;
  float*  dstf = (map ? t2f : t1f) + (size_t)b*Nn*Cc;

  const int nl = tid & 63;
  const int cb = tid >> 6;
  #pragma unroll
  for (int i = 0; i < 16; ++i) {
    const int c = cb + i*4;
    tile[nl][c] = src[(size_t)(c0 + c)*Nn + n0 + nl];
  }
  __syncthreads();
  #pragma unroll
  for (int j = 0; j < 4; ++j) {
    const int idx = j*256 + tid;
    const int n = idx >> 4, c4 = idx & 15;
    float v0 = tile[n][c4*4+0], v1 = tile[n][c4*4+1];
    float v2 = tile[n][c4*4+2], v3 = tile[n][c4*4+3];
    const size_t obase = (size_t)(n0 + n)*Cc + c0 + c4*4;
    float4 vf = make_float4(v0, v1, v2, v3);
    *(float4*)(dstf + obase) = vf;
    ushort4 ub = make_ushort4(f2bf(v0), f2bf(v1), f2bf(v2), f2bf(v3));
    *(ushort4*)(dstb + obase) = ub;
  }
}

// ---------------------------------------------------------------------------
// Kernel B: bf16 MFMA correlation + in-register per-row approximate top-8.
// 768 blocks x 256 thr (4 waves). Tile: 64 f1-rows x 1536 f2-cols, K=256.
// A-operand = f2 cols (wave-private 64-col quadrant), B-operand = f1 rows.
// f2 staged via global_load_lds, double-buffered 2x16KB, counted vmcnt(4),
// ZERO barriers in the main loop (wave-private producer-consumer).
// ---------------------------------------------------------------------------
__global__ __launch_bounds__(256, 2) void mfma_prefilter(
    const __bf16* __restrict__ f1t, const __bf16* __restrict__ f2t,
    float* __restrict__ pv, int* __restrict__ pix)
{
  __shared__ __bf16 As[64*256];      // f1 rows tile, 32 KB, swizzled granules
  __shared__ __bf16 Bs[2][256*32];   // f2 cols K-chunk double-buffer, 2x16 KB

  const int tid  = threadIdx.x;
  const int lane = tid & 63;
  const int wv   = tid >> 6;
  const int bid  = blockIdx.x;
  const int b    = bid / (96*SCH);
  const int r2   = bid % (96*SCH);
  const int row0 = (r2 >> 2) << 6;
  const int sc   = r2 & 3;
  const int col0 = sc * CPC;
  const size_t bN = (size_t)b * Nn;

  // ---- stage A (f1 rows, 64x256 K, 32 KB): 8 segs/wave, source pre-swizzled
  #pragma unroll
  for (int i = 0; i < 8; ++i) {
    const int seg = wv*8 + i;
    const int row = seg*2 + (lane >> 5);
    const int gs  = lane & 31;                       // dest granule in row
    const __bf16* gp = f1t + ((bN + row0 + row) << 8) + ((gs ^ (row & 7)) << 3);
    gld16(gp, (char*)As + seg*1024);
  }

  // ---- per-lane source offsets for B staging (wave-private col quadrant)
  size_t offB[4];
  #pragma unroll
  for (int i = 0; i < 4; ++i) {
    const int cl = wv*64 + i*16 + (lane >> 2);       // col within 1536-chunk
    const int g2 = (lane & 3) ^ ((cl >> 1) & 3);     // source granule in chunk
    offB[i] = ((bN + col0 + cl) << 8) + (g2 << 3);
  }
  #define STAGE_B(q, elemoff) do {                                        \
    _Pragma("unroll")                                                     \
    for (int _i = 0; _i < 4; ++_i)                                        \
      gld16(f2t + offB[_i] + (elemoff),                                   \
            (char*)&Bs[q][0] + wv*4096 + _i*1024);                        \
  } while (0)

  STAGE_B(0, 0);                                     // iter0 chunk0
  asm volatile("s_waitcnt vmcnt(4)" ::: "memory");   // A landed (B0 in flight)
  __builtin_amdgcn_sched_barrier(0);
  __syncthreads();                                   // A visible to all waves

  float va[4][8]; int ia[4][8];
  #pragma unroll
  for (int cg = 0; cg < 4; ++cg)
    #pragma unroll
    for (int j = 0; j < 8; ++j) { va[cg][j] = -INFINITY; ia[cg][j] = 0; }

  for (int iter = 0; iter < NITER; ++iter) {
    f32x4v acc[4][4];
    #pragma unroll
    for (int rg = 0; rg < 4; ++rg)
      #pragma unroll
      for (int cg = 0; cg < 4; ++cg)
        acc[rg][cg] = (f32x4v){0.f, 0.f, 0.f, 0.f};

    #pragma unroll
    for (int kc = 0; kc < 8; ++kc) {
      if (kc < 7) {
        STAGE_B((kc+1)&1, (size_t)iter*65536 + (kc+1)*32);
        asm volatile("s_waitcnt vmcnt(4)" ::: "memory");
      } else if (iter < NITER-1) {
        STAGE_B(0, (size_t)(iter+1)*65536);
        asm volatile("s_waitcnt vmcnt(4)" ::: "memory");
      } else {
        asm volatile("s_waitcnt vmcnt(0)" ::: "memory");
      }
      __builtin_amdgcn_sched_barrier(0);

      bf16x8 af[4], bfr[4];
      const int q = kc & 1;
      #pragma unroll
      for (int rg = 0; rg < 4; ++rg) {               // f2 cols (A-operand)
        const int cl = wv*64 + rg*16 + (lane & 15);
        const int gsw = (lane >> 4) ^ ((cl >> 1) & 3);
        af[rg] = *(const bf16x8*)((const char*)&Bs[q][0] + cl*64 + gsw*16);
      }
      #pragma unroll
      for (int cg = 0; cg < 4; ++cg) {               // f1 rows (B-operand)
        const int rw = cg*16 + (lane & 15);
        const int gas = (kc*4 + (lane >> 4)) ^ (rw & 7);
        bfr[cg] = *(const bf16x8*)((const char*)As + rw*512 + gas*16);
      }
      __builtin_amdgcn_s_setprio(1);
      #pragma unroll
      for (int rg = 0; rg < 4; ++rg)
        #pragma unroll
        for (int cg = 0; cg < 4; ++cg)
          acc[rg][cg] = __builtin_amdgcn_mfma_f32_16x16x32_bf16(
              af[rg], bfr[cg], acc[rg][cg], 0, 0, 0);
      __builtin_amdgcn_s_setprio(0);
    }

    // in-register top-8 update: D[f2col][f1row]; f1row = cg*16+(lane&15) (static cg)
    const int colB = col0 + iter*256 + wv*64 + ((lane >> 4) << 2);
    #pragma unroll
    for (int cg = 0; cg < 4; ++cg)
      #pragma unroll
      for (int rg = 0; rg < 4; ++rg)
        #pragma unroll
        for (int j = 0; j < 4; ++j)
          TOPK_INS(acc[rg][cg][j], colB + rg*16 + j, va[cg], ia[cg], 8);
  }

  // ---- final merge: 16 thread-lists per row -> top-8 per row ----
  __syncthreads();
  float* mv = (float*)As;            // 64*128 floats = 32 KB
  int*   mi = (int*)&Bs[0][0];       // 64*128 ints   = 32 KB
  const int slot = wv*4 + (lane >> 4);
  #pragma unroll
  for (int cg = 0; cg < 4; ++cg) {
    const int row = cg*16 + (lane & 15);
    #pragma unroll
    for (int j = 0; j < 8; ++j) {
      mv[row*128 + slot*8 + j] = va[cg][j];
      mi[row*128 + slot*8 + j] = ia[cg][j];
    }
  }
  __syncthreads();
  if (tid < 64) {
    float tv[8]; int ti[8];
    #pragma unroll
    for (int j = 0; j < 8; ++j) { tv[j] = -INFINITY; ti[j] = 0; }
    for (int e = 0; e < 128; ++e) {
      const int e2 = (e + tid) & 127;                // rotate: spread banks
      TOPK_INS(mv[tid*128 + e2], mi[tid*128 + e2], tv, ti, 8);
    }
    const size_t base = (bN + row0 + tid)*32 + sc*8;
    #pragma unroll
    for (int j = 0; j < 8; ++j) { pv[base + j] = tv[j]; pix[base + j] = ti[j]; }
  }
}

// ---------------------------------------------------------------------------
// Kernel C: merge 32 approx candidates -> top-16 -> exact fp32 rescore ->
// exact top-8 per pixel. 192 blocks (64 n each), 256 threads.
// ---------------------------------------------------------------------------
__global__ __launch_bounds__(256) void rescore_select(
    const float* __restrict__ pv, const int* __restrict__ pix,
    const float* __restrict__ t1f, const float* __restrict__ t2f,
    float* __restrict__ fv, int* __restrict__ fi)
{
  __shared__ int   cidx[64][16];
  __shared__ float cex[64][16];

  const int tid = threadIdx.x;
  const int bid = blockIdx.x;
  const int b   = bid / 96;
  const int n0  = (bid % 96) * 64;
  const size_t bn0 = (size_t)b*Nn + n0;

  // phase 1: one thread per n: approx top-16 of 32
  if (tid < 64) {
    float va[16]; int ia[16];
    #pragma unroll
    for (int j = 0; j < 16; ++j) { va[j] = -INFINITY; ia[j] = 0; }
    const size_t base = (bn0 + tid)*32;
    for (int e = 0; e < 32; ++e)
      TOPK_INS(pv[base + e], pix[base + e], va, ia, 16);
    #pragma unroll
    for (int j = 0; j < 16; ++j) cidx[tid][j] = ia[j];
  }
  __syncthreads();

  // phase 2: exact fp32 rescore: wave per 16 n, 4 lanes per candidate
  {
    const int w = tid >> 6, lane = tid & 63;
    const int cg = lane >> 2, li = lane & 3;
    for (int s = 0; s < 16; ++s) {
      const int nl = w*16 + s;
      const int m = cidx[nl][cg];
      const float4* p1 = (const float4*)(t1f + (bn0 + nl)*256 + li*64);
      const float4* p2 = (const float4*)(t2f + ((size_t)b*Nn + m)*256 + li*64);
      float sum = 0.f;
      #pragma unroll
      for (int j = 0; j < 16; ++j) {
        float4 a = p1[j], c = p2[j];
        sum += a.x*c.x + a.y*c.y + a.z*c.z + a.w*c.w;
      }
      sum += __shfl_xor(sum, 1);
      sum += __shfl_xor(sum, 2);
      if (li == 0) cex[nl][cg] = sum;
    }
  }
  __syncthreads();

  // phase 3: exact top-8 of 16, write final
  if (tid < 64) {
    float va[8]; int ia[8];
    #pragma unroll
    for (int j = 0; j < 8; ++j) { va[j] = -INFINITY; ia[j] = 0; }
    #pragma unroll
    for (int e = 0; e < 16; ++e)
      TOPK_INS(cex[tid][e], cidx[tid][e], va, ia, 8);
    const size_t base = (bn0 + tid)*8;
    #pragma unroll
    for (int j = 0; j < 8; ++j) { fv[base+j] = va[j]; fi[base+j] = ia[j]; }
  }
}

// ---------------------------------------------------------------------------
// Kernel D: displacement -> 5-level bilinear scatter
// ---------------------------------------------------------------------------
__global__ __launch_bounds__(128) void pyramid_kernel(
    const float* __restrict__ fv, const int* __restrict__ fi,
    const float* __restrict__ flow, float* __restrict__ out)
{
  __shared__ float accs[128*81];
  const int tid = threadIdx.x;
  const int g   = blockIdx.x*128 + tid;   // b*N + n
  const int lvl = blockIdx.y;
  const int b   = g / Nn;
  const int n   = g % Nn;

  float tvv[8]; int ti[8];
  #pragma unroll
  for (int k = 0; k < 8; ++k) { tvv[k] = fv[(size_t)g*8 + k]; ti[k] = fi[(size_t)g*8 + k]; }

  const int y = n / Ww, x = n % Ww;
  const float fly = flow[((size_t)b*2 + 1)*Nn + n];
  const float flx = flow[((size_t)b*2 + 0)*Nn + n];
  const float scale = 1.0f / (float)(1 << lvl);

  float* lacc = &accs[tid*81];
  #pragma unroll
  for (int c2 = 0; c2 < 81; ++c2) lacc[c2] = 0.f;

  #pragma unroll
  for (int k = 0; k < 8; ++k) {
    const int m  = ti[k];
    const int ym = m / Ww, xm = m % Ww;
    const float val = tvv[k] * 0.0625f;
    const float cy = ((float)(ym - y) - fly) * scale;
    const float cx = ((float)(xm - x) - flx) * scale;
    const float fy0 = floorf(cy), fx0 = floorf(cx);
    const float ry = cy - fy0, rx = cx - fx0;
    const int iy = (int)fy0, ix = (int)fx0;
    if (iy   >= -4 && iy   <= 4 && ix   >= -4 && ix   <= 4)
      lacc[(iy+4)*9 + (ix+4)]     += (1.f-ry)*(1.f-rx)*val;
    if (iy   >= -4 && iy   <= 4 && ix+1 >= -4 && ix+1 <= 4)
      lacc[(iy+4)*9 + (ix+1+4)]   += (1.f-ry)*rx*val;
    if (iy+1 >= -4 && iy+1 <= 4 && ix   >= -4 && ix   <= 4)
      lacc[(iy+1+4)*9 + (ix+4)]   += ry*(1.f-rx)*val;
    if (iy+1 >= -4 && iy+1 <= 4 && ix+1 >= -4 && ix+1 <= 4)
      lacc[(iy+1+4)*9 + (ix+1+4)] += ry*rx*val;
  }

  const size_t obase = ((size_t)b*(NLEV*81) + lvl*81) * Nn + n;
  #pragma unroll
  for (int c2 = 0; c2 < 81; ++c2)
    out[obase + (size_t)c2*Nn] = lacc[c2];
}

// ---------------------------------------------------------------------------
extern "C" void kernel_launch(void* const* d_in, const int* in_sizes, int n_in,
                              void* d_out, int out_size, void* d_ws, size_t ws_size,
                              hipStream_t stream) {
  const float* fmap1 = (const float*)d_in[0];
  const float* fmap2 = (const float*)d_in[1];
  const float* flow  = (const float*)d_in[2];
  float* out = (float*)d_out;

  char* w = (char*)d_ws;
  const size_t szBf  = (size_t)Bn*Nn*Cc*sizeof(unsigned short); // 6.29 MB
  const size_t szF   = (size_t)Bn*Nn*Cc*sizeof(float);          // 12.58 MB
  const size_t szPv  = (size_t)Bn*Nn*32*sizeof(float);          // 1.57 MB
  const size_t szFv  = (size_t)Bn*Nn*8*sizeof(float);           // 0.39 MB

  __bf16* t1b = (__bf16*)(w);
  __bf16* t2b = (__bf16*)(w + szBf);
  float*  t1f = (float*)(w + 2*szBf);
  float*  t2f = (float*)(w + 2*szBf + szF);
  float*  pv  = (float*)(w + 2*szBf + 2*szF);
  int*    pix = (int*)  (w + 2*szBf + 2*szF + szPv);
  float*  fv  = (float*)(w + 2*szBf + 2*szF + 2*szPv);
  int*    fi  = (int*)  (w + 2*szBf + 2*szF + 2*szPv + szFv);

  transpose_convert<<<dim3(1536), dim3(256), 0, stream>>>(fmap1, fmap2, t1b, t2b, t1f, t2f);
  mfma_prefilter  <<<dim3(Bn*96*SCH), dim3(256), 0, stream>>>(t1b, t2b, pv, pix);
  rescore_select  <<<dim3(192),  dim3(256), 0, stream>>>(pv, pix, t1f, t2f, fv, fi);
  pyramid_kernel  <<<dim3(96, NLEV), dim3(128), 0, stream>>>(fv, fi, flow, out);
}

// Round 5
// 233.160 us; speedup vs baseline: 3.3497x; 1.6609x over previous
//
#include <hip/hip_runtime.h>
#include <math.h>

#define Bn 2
#define Cc 256
#define Hh 64
#define Ww 96
#define Nn (Hh*Ww)       // 6144
#define NLEV 5
#define SCH 4            // column chunks (blocks) per row-tile
#define CPC (Nn/SCH)     // 1536 cols per block
#define NITER (CPC/256)  // 6 col-iterations of 256 cols
#define KNEG __uint_as_float(0xFF7FFFFFu)   // most-negative finite float

typedef __bf16 bf16x8 __attribute__((ext_vector_type(8)));
typedef float f32x4v __attribute__((ext_vector_type(4)));

// branchless sorted-descending insert of packed key into VA[LEN] (v_max/v_min ladder)
#define KEY_INS(k, VA, LEN) do {                                          \
  float _c = (k);                                                         \
  _Pragma("unroll")                                                       \
  for (int _s = 0; _s < (LEN); ++_s) {                                    \
    float _h = fmaxf(VA[_s], _c);                                         \
    _c = fminf(VA[_s], _c);                                               \
    VA[_s] = _h;                                                          \
  }                                                                       \
} while (0)

// legacy exact (value,index) insert — used only in tiny rescore phases
#define TOPK_INS(v, ix, VA, IA, LEN) do {                                 \
  if ((v) > VA[(LEN)-1]) {                                                \
    VA[(LEN)-1] = (v); IA[(LEN)-1] = (ix);                                \
    _Pragma("unroll")                                                     \
    for (int _s = (LEN)-1; _s > 0; --_s) {                                \
      if (VA[_s] > VA[_s-1]) {                                            \
        float _t = VA[_s]; VA[_s] = VA[_s-1]; VA[_s-1] = _t;              \
        int   _u = IA[_s]; IA[_s] = IA[_s-1]; IA[_s-1] = _u;              \
      }                                                                   \
    }                                                                     \
  }                                                                       \
} while (0)

__device__ __forceinline__ void gld16(const void* g, void* l) {
  __builtin_amdgcn_global_load_lds(
      (const __attribute__((address_space(1))) void*)g,
      (__attribute__((address_space(3))) void*)l, 16, 0, 0);
}

__device__ inline unsigned short f2bf(float f) {
  __bf16 h = (__bf16)f;
  return __builtin_bit_cast(unsigned short, h);
}

// ---------------------------------------------------------------------------
// Kernel A: [C][N] fp32 -> [N][C] bf16 + [N][C] fp32 (transpose + convert)
// ---------------------------------------------------------------------------
__global__ __launch_bounds__(256) void transpose_convert(
    const float* __restrict__ f1, const float* __restrict__ f2,
    __bf16* __restrict__ t1b, __bf16* __restrict__ t2b,
    float* __restrict__ t1f, float* __restrict__ t2f)
{
  __shared__ float tile[64][65];
  const int tid = threadIdx.x;
  const int bid = blockIdx.x;
  const int map = bid / 768;
  const int rem = bid % 768;
  const int b   = rem / 384;
  const int r2  = rem % 384;
  const int c0  = (r2 / 96) * 64;
  const int n0  = (r2 % 96) * 64;

  const float* src = (map ? f2 : f1) + (size_t)b*Cc*Nn;
  __bf16* dstb = (map ? t2b : t1b) + (size_t)b*Nn*Cc;
  float*  dstf = (map ? t2f : t1f) + (size_t)b*Nn*Cc;

  const int nl = tid & 63;
  const int cb = tid >> 6;
  #pragma unroll
  for (int i = 0; i < 16; ++i) {
    const int c = cb + i*4;
    tile[nl][c] = src[(size_t)(c0 + c)*Nn + n0 + nl];
  }
  __syncthreads();
  #pragma unroll
  for (int j = 0; j < 4; ++j) {
    const int idx = j*256 + tid;
    const int n = idx >> 4, c4 = idx & 15;
    float v0 = tile[n][c4*4+0], v1 = tile[n][c4*4+1];
    float v2 = tile[n][c4*4+2], v3 = tile[n][c4*4+3];
    const size_t obase = (size_t)(n0 + n)*Cc + c0 + c4*4;
    float4 vf = make_float4(v0, v1, v2, v3);
    *(float4*)(dstf + obase) = vf;
    ushort4 ub = make_ushort4(f2bf(v0), f2bf(v1), f2bf(v2), f2bf(v3));
    *(ushort4*)(dstb + obase) = ub;
  }
}

// ---------------------------------------------------------------------------
// Kernel B: bf16 MFMA correlation + in-register packed-key top-8 prefilter.
// 768 blocks x 256 thr (4 waves). Tile: 64 f1-rows x 1536 f2-cols, K=256.
// key = (acc_bits & 0xFFFFE000) | col13 -> branchless v_max/v_min ladder.
// f1 fragments kc=0..5 hoisted to registers (iter-invariant, -40% LDS reads).
// f2 staged via global_load_lds, double-buffered, counted vmcnt(4), no
// barriers in the main loop (wave-private quadrants).
// ---------------------------------------------------------------------------
__global__ __launch_bounds__(256, 2) void mfma_prefilter(
    const __bf16* __restrict__ f1t, const __bf16* __restrict__ f2t,
    unsigned* __restrict__ pv)
{
  __shared__ __align__(16) char smem[65536];
  __bf16* As = (__bf16*)smem;            // 32 KB f1 tile, swizzled granules
  // Bs double-buffer at smem+32768 (+q*16384), 2x16 KB
  unsigned* mk = (unsigned*)smem;        // merge keys: [64][133] u32 (34 KB)

  const int tid  = threadIdx.x;
  const int lane = tid & 63;
  const int wv   = tid >> 6;
  const int bid  = blockIdx.x;
  const int b    = bid / (96*SCH);
  const int r2   = bid % (96*SCH);
  const int row0 = (r2 >> 2) << 6;
  const int sc   = r2 & 3;
  const int col0 = sc * CPC;
  const size_t bN = (size_t)b * Nn;

  // ---- stage A (f1 rows, 64x256 K, 32 KB): source pre-swizzled
  #pragma unroll
  for (int i = 0; i < 8; ++i) {
    const int seg = wv*8 + i;
    const int row = seg*2 + (lane >> 5);
    const int gs  = lane & 31;
    const __bf16* gp = f1t + ((bN + row0 + row) << 8) + ((gs ^ (row & 7)) << 3);
    gld16(gp, smem + seg*1024);
  }

  // ---- per-lane source offsets for B staging (wave-private col quadrant)
  size_t offB[4];
  #pragma unroll
  for (int i = 0; i < 4; ++i) {
    const int cl = wv*64 + i*16 + (lane >> 2);
    const int g2 = (lane & 3) ^ ((cl >> 1) & 3);
    offB[i] = ((bN + col0 + cl) << 8) + (g2 << 3);
  }
  #define STAGE_B(q, elemoff) do {                                        \
    _Pragma("unroll")                                                     \
    for (int _i = 0; _i < 4; ++_i)                                        \
      gld16(f2t + offB[_i] + (elemoff),                                   \
            smem + 32768 + (q)*16384 + wv*4096 + _i*1024);                \
  } while (0)

  STAGE_B(0, 0);                                     // iter0 chunk0
  asm volatile("s_waitcnt vmcnt(4)" ::: "memory");   // A landed (B0 in flight)
  __builtin_amdgcn_sched_barrier(0);
  __syncthreads();                                   // A visible to all waves

  // ---- hoist f1 fragments for kc=0..5 into registers (iter-invariant)
  bf16x8 bfrH[4][6];
  #pragma unroll
  for (int kc = 0; kc < 6; ++kc)
    #pragma unroll
    for (int cg = 0; cg < 4; ++cg) {
      const int rw = cg*16 + (lane & 15);
      const int gas = (kc*4 + (lane >> 4)) ^ (rw & 7);
      bfrH[cg][kc] = *(const bf16x8*)((const char*)As + rw*512 + gas*16);
    }

  float va[4][8];
  #pragma unroll
  for (int cg = 0; cg < 4; ++cg)
    #pragma unroll
    for (int j = 0; j < 8; ++j) va[cg][j] = KNEG;

  for (int iter = 0; iter < NITER; ++iter) {
    f32x4v acc[4][4];
    #pragma unroll
    for (int rg = 0; rg < 4; ++rg)
      #pragma unroll
      for (int cg = 0; cg < 4; ++cg)
        acc[rg][cg] = (f32x4v){0.f, 0.f, 0.f, 0.f};

    #pragma unroll
    for (int kc = 0; kc < 8; ++kc) {
      if (kc < 7) {
        STAGE_B((kc+1)&1, (size_t)iter*65536 + (kc+1)*32);
        asm volatile("s_waitcnt vmcnt(4)" ::: "memory");
      } else if (iter < NITER-1) {
        STAGE_B(0, (size_t)(iter+1)*65536);
        asm volatile("s_waitcnt vmcnt(4)" ::: "memory");
      } else {
        asm volatile("s_waitcnt vmcnt(0)" ::: "memory");
      }
      __builtin_amdgcn_sched_barrier(0);

      bf16x8 af[4], bfr[4];
      const int q = kc & 1;
      #pragma unroll
      for (int rg = 0; rg < 4; ++rg) {               // f2 cols (A-operand)
        const int cl = wv*64 + rg*16 + (lane & 15);
        const int gsw = (lane >> 4) ^ ((cl >> 1) & 3);
        af[rg] = *(const bf16x8*)(smem + 32768 + q*16384 + cl*64 + gsw*16);
      }
      #pragma unroll
      for (int cg = 0; cg < 4; ++cg) {               // f1 rows (B-operand)
        if (kc < 6) {
          bfr[cg] = bfrH[cg][kc];
        } else {
          const int rw = cg*16 + (lane & 15);
          const int gas = (kc*4 + (lane >> 4)) ^ (rw & 7);
          bfr[cg] = *(const bf16x8*)((const char*)As + rw*512 + gas*16);
        }
      }
      __builtin_amdgcn_s_setprio(1);
      #pragma unroll
      for (int rg = 0; rg < 4; ++rg)
        #pragma unroll
        for (int cg = 0; cg < 4; ++cg)
          acc[rg][cg] = __builtin_amdgcn_mfma_f32_16x16x32_bf16(
              af[rg], bfr[cg], acc[rg][cg], 0, 0, 0);
      __builtin_amdgcn_s_setprio(0);
    }

    // packed-key top-8 update: D[f2col][f1row], list per f1row (static cg)
    const int colB = col0 + iter*256 + wv*64 + ((lane >> 4) << 2);
    #pragma unroll
    for (int cg = 0; cg < 4; ++cg)
      #pragma unroll
      for (int rg = 0; rg < 4; ++rg)
        #pragma unroll
        for (int j = 0; j < 4; ++j) {
          const unsigned u =
              (__float_as_uint(acc[rg][cg][j]) & 0xFFFFE000u) |
              (unsigned)(colB + rg*16 + j);
          const float k = __uint_as_float(u);
          KEY_INS(k, va[cg], 8);
        }
  }

  // ---- final merge: 16 key-lists per row -> top-8 per row ----
  __syncthreads();
  const int slot = wv*4 + (lane >> 4);
  #pragma unroll
  for (int cg = 0; cg < 4; ++cg) {
    const int row = cg*16 + (lane & 15);
    #pragma unroll
    for (int j = 0; j < 8; ++j)
      mk[row*133 + slot*8 + j] = __float_as_uint(va[cg][j]);
  }
  __syncthreads();
  if (tid < 64) {
    float tv[8];
    #pragma unroll
    for (int j = 0; j < 8; ++j) tv[j] = KNEG;
    for (int e = 0; e < 128; ++e)
      KEY_INS(__uint_as_float(mk[tid*133 + e]), tv, 8);
    const size_t base = (bN + row0 + tid)*32 + sc*8;
    #pragma unroll
    for (int j = 0; j < 8; ++j) pv[base + j] = __float_as_uint(tv[j]);
  }
}

// ---------------------------------------------------------------------------
// Kernel C: merge 32 key candidates -> top-16 -> exact fp32 rescore ->
// exact top-8 per pixel. 192 blocks (64 n each), 256 threads.
// ---------------------------------------------------------------------------
__global__ __launch_bounds__(256) void rescore_select(
    const unsigned* __restrict__ pv,
    const float* __restrict__ t1f, const float* __restrict__ t2f,
    float* __restrict__ fv, int* __restrict__ fi)
{
  __shared__ int   cidx[64][16];
  __shared__ float cex[64][16];

  const int tid = threadIdx.x;
  const int bid = blockIdx.x;
  const int b   = bid / 96;
  const int n0  = (bid % 96) * 64;
  const size_t bn0 = (size_t)b*Nn + n0;

  // phase 1: one thread per n: key-ladder top-16 of 32
  if (tid < 64) {
    float va[16];
    #pragma unroll
    for (int j = 0; j < 16; ++j) va[j] = KNEG;
    const size_t base = (bn0 + tid)*32;
    for (int e = 0; e < 32; ++e)
      KEY_INS(__uint_as_float(pv[base + e]), va, 16);
    #pragma unroll
    for (int j = 0; j < 16; ++j)
      cidx[tid][j] = (int)(__float_as_uint(va[j]) & 0x1FFFu);
  }
  __syncthreads();

  // phase 2: exact fp32 rescore: wave per 16 n, 4 lanes per candidate
  {
    const int w = tid >> 6, lane = tid & 63;
    const int cg = lane >> 2, li = lane & 3;
    for (int s = 0; s < 16; ++s) {
      const int nl = w*16 + s;
      const int m = cidx[nl][cg];
      const float4* p1 = (const float4*)(t1f + (bn0 + nl)*256 + li*64);
      const float4* p2 = (const float4*)(t2f + ((size_t)b*Nn + m)*256 + li*64);
      float sum = 0.f;
      #pragma unroll
      for (int j = 0; j < 16; ++j) {
        float4 a = p1[j], c = p2[j];
        sum += a.x*c.x + a.y*c.y + a.z*c.z + a.w*c.w;
      }
      sum += __shfl_xor(sum, 1);
      sum += __shfl_xor(sum, 2);
      if (li == 0) cex[nl][cg] = sum;
    }
  }
  __syncthreads();

  // phase 3: exact top-8 of 16, write final
  if (tid < 64) {
    float va[8]; int ia[8];
    #pragma unroll
    for (int j = 0; j < 8; ++j) { va[j] = -INFINITY; ia[j] = 0; }
    #pragma unroll
    for (int e = 0; e < 16; ++e)
      TOPK_INS(cex[tid][e], cidx[tid][e], va, ia, 8);
    const size_t base = (bn0 + tid)*8;
    #pragma unroll
    for (int j = 0; j < 8; ++j) { fv[base+j] = va[j]; fi[base+j] = ia[j]; }
  }
}

// ---------------------------------------------------------------------------
// Kernel D: displacement -> 5-level bilinear scatter
// ---------------------------------------------------------------------------
__global__ __launch_bounds__(128) void pyramid_kernel(
    const float* __restrict__ fv, const int* __restrict__ fi,
    const float* __restrict__ flow, float* __restrict__ out)
{
  __shared__ float accs[128*81];
  const int tid = threadIdx.x;
  const int g   = blockIdx.x*128 + tid;   // b*N + n
  const int lvl = blockIdx.y;
  const int b   = g / Nn;
  const int n   = g % Nn;

  float tvv[8]; int ti[8];
  #pragma unroll
  for (int k = 0; k < 8; ++k) { tvv[k] = fv[(size_t)g*8 + k]; ti[k] = fi[(size_t)g*8 + k]; }

  const int y = n / Ww, x = n % Ww;
  const float fly = flow[((size_t)b*2 + 1)*Nn + n];
  const float flx = flow[((size_t)b*2 + 0)*Nn + n];
  const float scale = 1.0f / (float)(1 << lvl);

  float* lacc = &accs[tid*81];
  #pragma unroll
  for (int c2 = 0; c2 < 81; ++c2) lacc[c2] = 0.f;

  #pragma unroll
  for (int k = 0; k < 8; ++k) {
    const int m  = ti[k];
    const int ym = m / Ww, xm = m % Ww;
    const float val = tvv[k] * 0.0625f;
    const float cy = ((float)(ym - y) - fly) * scale;
    const float cx = ((float)(xm - x) - flx) * scale;
    const float fy0 = floorf(cy), fx0 = floorf(cx);
    const float ry = cy - fy0, rx = cx - fx0;
    const int iy = (int)fy0, ix = (int)fx0;
    if (iy   >= -4 && iy   <= 4 && ix   >= -4 && ix   <= 4)
      lacc[(iy+4)*9 + (ix+4)]     += (1.f-ry)*(1.f-rx)*val;
    if (iy   >= -4 && iy   <= 4 && ix+1 >= -4 && ix+1 <= 4)
      lacc[(iy+4)*9 + (ix+1+4)]   += (1.f-ry)*rx*val;
    if (iy+1 >= -4 && iy+1 <= 4 && ix   >= -4 && ix   <= 4)
      lacc[(iy+1+4)*9 + (ix+4)]   += ry*(1.f-rx)*val;
    if (iy+1 >= -4 && iy+1 <= 4 && ix+1 >= -4 && ix+1 <= 4)
      lacc[(iy+1+4)*9 + (ix+1+4)] += ry*rx*val;
  }

  const size_t obase = ((size_t)b*(NLEV*81) + lvl*81) * Nn + n;
  #pragma unroll
  for (int c2 = 0; c2 < 81; ++c2)
    out[obase + (size_t)c2*Nn] = lacc[c2];
}

// ---------------------------------------------------------------------------
extern "C" void kernel_launch(void* const* d_in, const int* in_sizes, int n_in,
                              void* d_out, int out_size, void* d_ws, size_t ws_size,
                              hipStream_t stream) {
  const float* fmap1 = (const float*)d_in[0];
  const float* fmap2 = (const float*)d_in[1];
  const float* flow  = (const float*)d_in[2];
  float* out = (float*)d_out;

  char* w = (char*)d_ws;
  const size_t szBf  = (size_t)Bn*Nn*Cc*sizeof(unsigned short); // 6.29 MB
  const size_t szF   = (size_t)Bn*Nn*Cc*sizeof(float);          // 12.58 MB
  const size_t szPv  = (size_t)Bn*Nn*32*sizeof(unsigned);       // 1.57 MB
  const size_t szFv  = (size_t)Bn*Nn*8*sizeof(float);           // 0.39 MB

  __bf16*   t1b = (__bf16*)(w);
  __bf16*   t2b = (__bf16*)(w + szBf);
  float*    t1f = (float*)(w + 2*szBf);
  float*    t2f = (float*)(w + 2*szBf + szF);
  unsigned* pv  = (unsigned*)(w + 2*szBf + 2*szF);
  float*    fv  = (float*)(w + 2*szBf + 2*szF + szPv);
  int*      fi  = (int*)  (w + 2*szBf + 2*szF + szPv + szFv);

  transpose_convert<<<dim3(1536), dim3(256), 0, stream>>>(fmap1, fmap2, t1b, t2b, t1f, t2f);
  mfma_prefilter  <<<dim3(Bn*96*SCH), dim3(256), 0, stream>>>(t1b, t2b, pv);
  rescore_select  <<<dim3(192),  dim3(256), 0, stream>>>(pv, t1f, t2f, fv, fi);
  pyramid_kernel  <<<dim3(96, NLEV), dim3(128), 0, stream>>>(fv, fi, flow, out);
}

// Round 6
// 192.368 us; speedup vs baseline: 4.0601x; 1.2121x over previous
//
#include <hip/hip_runtime.h>
#include <math.h>

#define Bn 2
#define Cc 256
#define Hh 64
#define Ww 96
#define Nn (Hh*Ww)       // 6144
#define NLEV 5
#define SCH 4            // column chunks per row-tile
#define CPC (Nn/SCH)     // 1536 cols per block
#define NITER (CPC/256)  // 6 col-iterations of 256 cols
#define TKEEP 6          // per-thread kept list length
#define KNEG __uint_as_float(0xFF7FFFFFu)   // most-negative finite float

typedef __bf16 bf16x8 __attribute__((ext_vector_type(8)));
typedef float f32x4v __attribute__((ext_vector_type(4)));

// branchless sorted-descending insert of packed key into VA[LEN]
#define KEY_INS(k, VA, LEN) do {                                          \
  float _c = (k);                                                         \
  _Pragma("unroll")                                                       \
  for (int _s = 0; _s < (LEN); ++_s) {                                    \
    float _h = fmaxf(VA[_s], _c);                                         \
    _c = fminf(VA[_s], _c);                                               \
    VA[_s] = _h;                                                          \
  }                                                                       \
} while (0)

// exact (value,index) insert — tiny rescore phases only
#define TOPK_INS(v, ix, VA, IA, LEN) do {                                 \
  if ((v) > VA[(LEN)-1]) {                                                \
    VA[(LEN)-1] = (v); IA[(LEN)-1] = (ix);                                \
    _Pragma("unroll")                                                     \
    for (int _s = (LEN)-1; _s > 0; --_s) {                                \
      if (VA[_s] > VA[_s-1]) {                                            \
        float _t = VA[_s]; VA[_s] = VA[_s-1]; VA[_s-1] = _t;              \
        int   _u = IA[_s]; IA[_s] = IA[_s-1]; IA[_s-1] = _u;              \
      }                                                                   \
    }                                                                     \
  }                                                                       \
} while (0)

__device__ __forceinline__ void gld16(const void* g, void* l) {
  __builtin_amdgcn_global_load_lds(
      (const __attribute__((address_space(1))) void*)g,
      (__attribute__((address_space(3))) void*)l, 16, 0, 0);
}

__device__ inline unsigned short f2bf(float f) {
  __bf16 h = (__bf16)f;
  return __builtin_bit_cast(unsigned short, h);
}

// ---------------------------------------------------------------------------
// Kernel A: [C][N] fp32 -> [N][C] bf16 + [N][C] fp32 (transpose + convert)
// ---------------------------------------------------------------------------
__global__ __launch_bounds__(256) void transpose_convert(
    const float* __restrict__ f1, const float* __restrict__ f2,
    __bf16* __restrict__ t1b, __bf16* __restrict__ t2b,
    float* __restrict__ t1f, float* __restrict__ t2f)
{
  __shared__ float tile[64][65];
  const int tid = threadIdx.x;
  const int bid = blockIdx.x;
  const int map = bid / 768;
  const int rem = bid % 768;
  const int b   = rem / 384;
  const int r2  = rem % 384;
  const int c0  = (r2 / 96) * 64;
  const int n0  = (r2 % 96) * 64;

  const float* src = (map ? f2 : f1) + (size_t)b*Cc*Nn;
  __bf16* dstb = (map ? t2b : t1b) + (size_t)b*Nn*Cc;
  float*  dstf = (map ? t2f : t1f) + (size_t)b*Nn*Cc;

  const int nl = tid & 63;
  const int cb = tid >> 6;
  #pragma unroll
  for (int i = 0; i < 16; ++i) {
    const int c = cb + i*4;
    tile[nl][c] = src[(size_t)(c0 + c)*Nn + n0 + nl];
  }
  __syncthreads();
  #pragma unroll
  for (int j = 0; j < 4; ++j) {
    const int idx = j*256 + tid;
    const int n = idx >> 4, c4 = idx & 15;
    float v0 = tile[n][c4*4+0], v1 = tile[n][c4*4+1];
    float v2 = tile[n][c4*4+2], v3 = tile[n][c4*4+3];
    const size_t obase = (size_t)(n0 + n)*Cc + c0 + c4*4;
    float4 vf = make_float4(v0, v1, v2, v3);
    *(float4*)(dstf + obase) = vf;
    ushort4 ub = make_ushort4(f2bf(v0), f2bf(v1), f2bf(v2), f2bf(v3));
    *(ushort4*)(dstb + obase) = ub;
  }
}

// ---------------------------------------------------------------------------
// Kernel B: bf16 MFMA correlation + packed-key per-thread top-6 prefilter.
// 1536 blocks x 256 thr (4 waves). Tile: 32 f1-rows x 1536 f2-cols, K=256.
// LDS 48 KB -> 3 blocks/CU (12 waves/CU); grid = 6/CU (two even rounds).
// ---------------------------------------------------------------------------
__global__ __launch_bounds__(256, 2) void mfma_prefilter(
    const __bf16* __restrict__ f1t, const __bf16* __restrict__ f2t,
    unsigned* __restrict__ pv)
{
  __shared__ __align__(16) char smem[49152];
  __bf16* As = (__bf16*)smem;            // 16 KB f1 tile (32 rows x 256 K)
  // Bs double-buffer at smem+16384 (+q*16384), 2x16 KB
  unsigned* mk = (unsigned*)smem;        // merge keys [32][97] u32 (12.4 KB)

  const int tid  = threadIdx.x;
  const int lane = tid & 63;
  const int wv   = tid >> 6;
  const int bid  = blockIdx.x;
  const int b    = bid / (192*SCH);
  const int r2   = bid % (192*SCH);
  const int row0 = (r2 >> 2) << 5;       // 192 row-tiles of 32
  const int sc   = r2 & 3;
  const int col0 = sc * CPC;
  const size_t bN = (size_t)b * Nn;

  // ---- stage A (32 rows x 256 K, 16 KB): source pre-swizzled
  #pragma unroll
  for (int i = 0; i < 4; ++i) {
    const int seg = wv*4 + i;            // 0..15, 1 KB each (2 rows)
    const int row = seg*2 + (lane >> 5);
    const int gs  = lane & 31;
    const __bf16* gp = f1t + ((bN + row0 + row) << 8) + ((gs ^ (row & 7)) << 3);
    gld16(gp, smem + seg*1024);
  }

  // ---- per-lane source offsets for B staging (wave-private col quadrant)
  size_t offB[4];
  #pragma unroll
  for (int i = 0; i < 4; ++i) {
    const int cl = wv*64 + i*16 + (lane >> 2);
    const int g2 = (lane & 3) ^ ((cl >> 1) & 3);
    offB[i] = ((bN + col0 + cl) << 8) + (g2 << 3);
  }
  #define STAGE_B(q, elemoff) do {                                        \
    _Pragma("unroll")                                                     \
    for (int _i = 0; _i < 4; ++_i)                                        \
      gld16(f2t + offB[_i] + (elemoff),                                   \
            smem + 16384 + (q)*16384 + wv*4096 + _i*1024);                \
  } while (0)

  STAGE_B(0, 0);
  asm volatile("s_waitcnt vmcnt(4)" ::: "memory");   // A landed (B0 in flight)
  __builtin_amdgcn_sched_barrier(0);
  __syncthreads();

  // ---- hoist f1 fragments for kc=0..5 (iter-invariant); kc 6,7 read live
  bf16x8 bfrH[2][6];
  #pragma unroll
  for (int kc = 0; kc < 6; ++kc)
    #pragma unroll
    for (int cg = 0; cg < 2; ++cg) {
      const int rw = cg*16 + (lane & 15);
      const int gas = (kc*4 + (lane >> 4)) ^ (rw & 7);
      bfrH[cg][kc] = *(const bf16x8*)((const char*)As + rw*512 + gas*16);
    }

  float va[2][TKEEP];
  #pragma unroll
  for (int cg = 0; cg < 2; ++cg)
    #pragma unroll
    for (int j = 0; j < TKEEP; ++j) va[cg][j] = KNEG;

  for (int iter = 0; iter < NITER; ++iter) {
    f32x4v acc[4][2];
    #pragma unroll
    for (int rg = 0; rg < 4; ++rg)
      #pragma unroll
      for (int cg = 0; cg < 2; ++cg)
        acc[rg][cg] = (f32x4v){0.f, 0.f, 0.f, 0.f};

    #pragma unroll
    for (int kc = 0; kc < 8; ++kc) {
      if (kc < 7) {
        STAGE_B((kc+1)&1, (size_t)iter*65536 + (kc+1)*32);
        asm volatile("s_waitcnt vmcnt(4)" ::: "memory");
      } else if (iter < NITER-1) {
        STAGE_B(0, (size_t)(iter+1)*65536);
        asm volatile("s_waitcnt vmcnt(4)" ::: "memory");
      } else {
        asm volatile("s_waitcnt vmcnt(0)" ::: "memory");
      }
      __builtin_amdgcn_sched_barrier(0);

      bf16x8 af[4], bfr[2];
      const int q = kc & 1;
      #pragma unroll
      for (int rg = 0; rg < 4; ++rg) {               // f2 cols (A-operand)
        const int cl = wv*64 + rg*16 + (lane & 15);
        const int gsw = (lane >> 4) ^ ((cl >> 1) & 3);
        af[rg] = *(const bf16x8*)(smem + 16384 + q*16384 + cl*64 + gsw*16);
      }
      #pragma unroll
      for (int cg = 0; cg < 2; ++cg) {               // f1 rows (B-operand)
        if (kc < 6) {
          bfr[cg] = bfrH[cg][kc];
        } else {
          const int rw = cg*16 + (lane & 15);
          const int gas = (kc*4 + (lane >> 4)) ^ (rw & 7);
          bfr[cg] = *(const bf16x8*)((const char*)As + rw*512 + gas*16);
        }
      }
      __builtin_amdgcn_s_setprio(1);
      #pragma unroll
      for (int rg = 0; rg < 4; ++rg)
        #pragma unroll
        for (int cg = 0; cg < 2; ++cg)
          acc[rg][cg] = __builtin_amdgcn_mfma_f32_16x16x32_bf16(
              af[rg], bfr[cg], acc[rg][cg], 0, 0, 0);
      __builtin_amdgcn_s_setprio(0);
    }

    // packed-key top-6 update: D[f2col][f1row], one list per f1row (static cg)
    const int colB = col0 + iter*256 + wv*64 + ((lane >> 4) << 2);
    #pragma unroll
    for (int cg = 0; cg < 2; ++cg)
      #pragma unroll
      for (int rg = 0; rg < 4; ++rg)
        #pragma unroll
        for (int j = 0; j < 4; ++j) {
          const unsigned u =
              (__float_as_uint(acc[rg][cg][j]) & 0xFFFFE000u) |
              (unsigned)(colB + rg*16 + j);
          KEY_INS(__uint_as_float(u), va[cg], TKEEP);
        }
  }

  // ---- final merge: 16 thread-lists per row (96 keys) -> top-8 per row ----
  __syncthreads();
  const int slot = wv*4 + (lane >> 4);
  #pragma unroll
  for (int cg = 0; cg < 2; ++cg) {
    const int row = cg*16 + (lane & 15);
    #pragma unroll
    for (int j = 0; j < TKEEP; ++j)
      mk[row*97 + slot*TKEEP + j] = __float_as_uint(va[cg][j]);
  }
  __syncthreads();
  if (tid < 32) {
    float tv[8];
    #pragma unroll
    for (int j = 0; j < 8; ++j) tv[j] = KNEG;
    for (int e = 0; e < 16*TKEEP; ++e)
      KEY_INS(__uint_as_float(mk[tid*97 + e]), tv, 8);
    const size_t base = (bN + row0 + tid)*32 + sc*8;
    #pragma unroll
    for (int j = 0; j < 8; ++j) pv[base + j] = __float_as_uint(tv[j]);
  }
}

// ---------------------------------------------------------------------------
// Kernel C: 32 keys -> approx top-16 -> exact fp32 rescore -> exact top-8.
// 768 blocks x 256 thr, 16 n each; f1 rows staged in LDS (read once);
// 8 lanes per candidate dot + shfl reduce.
// ---------------------------------------------------------------------------
__global__ __launch_bounds__(256) void rescore_select(
    const unsigned* __restrict__ pv,
    const float* __restrict__ t1f, const float* __restrict__ t2f,
    float* __restrict__ fv, int* __restrict__ fi)
{
  __shared__ float f1s[16][256];   // 16 KB
  __shared__ int   cidx[16][16];
  __shared__ float cex[16][16];

  const int tid = threadIdx.x;
  const int bid = blockIdx.x;
  const int b   = bid / 384;
  const int n0  = (bid % 384) * 16;
  const size_t bn0 = (size_t)b*Nn + n0;

  // stage f1 rows: 16 x 1 KB
  #pragma unroll
  for (int k = 0; k < 4; ++k) {
    const int r = (tid >> 6) + k*4;
    const int p = tid & 63;
    *(float4*)(&f1s[r][p*4]) = *(const float4*)(t1f + (bn0 + r)*256 + p*4);
  }

  // phase 1: one thread per n: key-ladder top-16 of 32
  if (tid < 16) {
    float va[16];
    #pragma unroll
    for (int j = 0; j < 16; ++j) va[j] = KNEG;
    const size_t base = (bn0 + tid)*32;
    for (int e = 0; e < 32; ++e)
      KEY_INS(__uint_as_float(pv[base + e]), va, 16);
    #pragma unroll
    for (int j = 0; j < 16; ++j)
      cidx[tid][j] = (int)(__float_as_uint(va[j]) & 0x1FFFu);
  }
  __syncthreads();

  // phase 2: exact fp32 rescore: wave handles 4 n; 8 lanes per candidate
  {
    const int lane = tid & 63;
    const int cg = lane >> 3, li = lane & 7;
    #pragma unroll
    for (int nn = 0; nn < 4; ++nn) {
      const int nl = (tid >> 6)*4 + nn;
      #pragma unroll
      for (int p = 0; p < 2; ++p) {
        const int cand = p*8 + cg;
        const int m = cidx[nl][cand];
        const float4* p2 = (const float4*)(t2f + ((size_t)b*Nn + m)*256);
        float sum = 0.f;
        #pragma unroll
        for (int j = 0; j < 8; ++j) {
          const int fi4 = j*8 + li;
          float4 a = *(const float4*)(&f1s[nl][fi4*4]);
          float4 c = p2[fi4];
          sum += a.x*c.x + a.y*c.y + a.z*c.z + a.w*c.w;
        }
        sum += __shfl_xor(sum, 1);
        sum += __shfl_xor(sum, 2);
        sum += __shfl_xor(sum, 4);
        if (li == 0) cex[nl][cand] = sum;
      }
    }
  }
  __syncthreads();

  // phase 3: exact top-8 of 16, write final
  if (tid < 16) {
    float va[8]; int ia[8];
    #pragma unroll
    for (int j = 0; j < 8; ++j) { va[j] = -INFINITY; ia[j] = 0; }
    #pragma unroll
    for (int e = 0; e < 16; ++e)
      TOPK_INS(cex[tid][e], cidx[tid][e], va, ia, 8);
    const size_t base = (bn0 + tid)*8;
    #pragma unroll
    for (int j = 0; j < 8; ++j) { fv[base+j] = va[j]; fi[base+j] = ia[j]; }
  }
}

// ---------------------------------------------------------------------------
// Kernel D: displacement -> 5-level bilinear scatter
// ---------------------------------------------------------------------------
__global__ __launch_bounds__(128) void pyramid_kernel(
    const float* __restrict__ fv, const int* __restrict__ fi,
    const float* __restrict__ flow, float* __restrict__ out)
{
  __shared__ float accs[128*81];
  const int tid = threadIdx.x;
  const int g   = blockIdx.x*128 + tid;   // b*N + n
  const int lvl = blockIdx.y;
  const int b   = g / Nn;
  const int n   = g % Nn;

  float tvv[8]; int ti[8];
  #pragma unroll
  for (int k = 0; k < 8; ++k) { tvv[k] = fv[(size_t)g*8 + k]; ti[k] = fi[(size_t)g*8 + k]; }

  const int y = n / Ww, x = n % Ww;
  const float fly = flow[((size_t)b*2 + 1)*Nn + n];
  const float flx = flow[((size_t)b*2 + 0)*Nn + n];
  const float scale = 1.0f / (float)(1 << lvl);

  float* lacc = &accs[tid*81];
  #pragma unroll
  for (int c2 = 0; c2 < 81; ++c2) lacc[c2] = 0.f;

  #pragma unroll
  for (int k = 0; k < 8; ++k) {
    const int m  = ti[k];
    const int ym = m / Ww, xm = m % Ww;
    const float val = tvv[k] * 0.0625f;
    const float cy = ((float)(ym - y) - fly) * scale;
    const float cx = ((float)(xm - x) - flx) * scale;
    const float fy0 = floorf(cy), fx0 = floorf(cx);
    const float ry = cy - fy0, rx = cx - fx0;
    const int iy = (int)fy0, ix = (int)fx0;
    if (iy   >= -4 && iy   <= 4 && ix   >= -4 && ix   <= 4)
      lacc[(iy+4)*9 + (ix+4)]     += (1.f-ry)*(1.f-rx)*val;
    if (iy   >= -4 && iy   <= 4 && ix+1 >= -4 && ix+1 <= 4)
      lacc[(iy+4)*9 + (ix+1+4)]   += (1.f-ry)*rx*val;
    if (iy+1 >= -4 && iy+1 <= 4 && ix   >= -4 && ix   <= 4)
      lacc[(iy+1+4)*9 + (ix+4)]   += ry*(1.f-rx)*val;
    if (iy+1 >= -4 && iy+1 <= 4 && ix+1 >= -4 && ix+1 <= 4)
      lacc[(iy+1+4)*9 + (ix+1+4)] += ry*rx*val;
  }

  const size_t obase = ((size_t)b*(NLEV*81) + lvl*81) * Nn + n;
  #pragma unroll
  for (int c2 = 0; c2 < 81; ++c2)
    out[obase + (size_t)c2*Nn] = lacc[c2];
}

// ---------------------------------------------------------------------------
extern "C" void kernel_launch(void* const* d_in, const int* in_sizes, int n_in,
                              void* d_out, int out_size, void* d_ws, size_t ws_size,
                              hipStream_t stream) {
  const float* fmap1 = (const float*)d_in[0];
  const float* fmap2 = (const float*)d_in[1];
  const float* flow  = (const float*)d_in[2];
  float* out = (float*)d_out;

  char* w = (char*)d_ws;
  const size_t szBf  = (size_t)Bn*Nn*Cc*sizeof(unsigned short); // 6.29 MB
  const size_t szF   = (size_t)Bn*Nn*Cc*sizeof(float);          // 12.58 MB
  const size_t szPv  = (size_t)Bn*Nn*32*sizeof(unsigned);       // 1.57 MB
  const size_t szFv  = (size_t)Bn*Nn*8*sizeof(float);           // 0.39 MB

  __bf16*   t1b = (__bf16*)(w);
  __bf16*   t2b = (__bf16*)(w + szBf);
  float*    t1f = (float*)(w + 2*szBf);
  float*    t2f = (float*)(w + 2*szBf + szF);
  unsigned* pv  = (unsigned*)(w + 2*szBf + 2*szF);
  float*    fv  = (float*)(w + 2*szBf + 2*szF + szPv);
  int*      fi  = (int*)  (w + 2*szBf + 2*szF + szPv + szFv);

  transpose_convert<<<dim3(1536), dim3(256), 0, stream>>>(fmap1, fmap2, t1b, t2b, t1f, t2f);
  mfma_prefilter  <<<dim3(Bn*192*SCH), dim3(256), 0, stream>>>(t1b, t2b, pv);
  rescore_select  <<<dim3(768),  dim3(256), 0, stream>>>(pv, t1f, t2f, fv, fi);
  pyramid_kernel  <<<dim3(96, NLEV), dim3(128), 0, stream>>>(fv, fi, flow, out);
}

// Round 7
// 177.263 us; speedup vs baseline: 4.4060x; 1.0852x over previous
//
#include <hip/hip_runtime.h>
#include <math.h>

#define Bn 2
#define Cc 256
#define Hh 64
#define Ww 96
#define Nn (Hh*Ww)       // 6144
#define NLEV 5
#define SCH 4            // column chunks per row-tile
#define CPC (Nn/SCH)     // 1536 cols per block
#define ROWT 48          // rows per block tile
#define NITER (CPC/128)  // 12 col-iterations of 128 cols
#define HOIST 3          // f1 fragments hoisted for kc<HOIST
#define TKEEP 6          // per-thread kept list length
#define KNEG __uint_as_float(0xFF7FFFFFu)   // most-negative finite float

typedef __bf16 bf16x8 __attribute__((ext_vector_type(8)));
typedef float f32x4v __attribute__((ext_vector_type(4)));

// branchless sorted-descending insert of packed key into VA[LEN]
#define KEY_INS(k, VA, LEN) do {                                          \
  float _c = (k);                                                         \
  _Pragma("unroll")                                                       \
  for (int _s = 0; _s < (LEN); ++_s) {                                    \
    float _h = fmaxf(VA[_s], _c);                                         \
    _c = fminf(VA[_s], _c);                                               \
    VA[_s] = _h;                                                          \
  }                                                                       \
} while (0)

// exact (value,index) insert — tiny rescore phases only
#define TOPK_INS(v, ix, VA, IA, LEN) do {                                 \
  if ((v) > VA[(LEN)-1]) {                                                \
    VA[(LEN)-1] = (v); IA[(LEN)-1] = (ix);                                \
    _Pragma("unroll")                                                     \
    for (int _s = (LEN)-1; _s > 0; --_s) {                                \
      if (VA[_s] > VA[_s-1]) {                                            \
        float _t = VA[_s]; VA[_s] = VA[_s-1]; VA[_s-1] = _t;              \
        int   _u = IA[_s]; IA[_s] = IA[_s-1]; IA[_s-1] = _u;              \
      }                                                                   \
    }                                                                     \
  }                                                                       \
} while (0)

__device__ __forceinline__ void gld16(const void* g, void* l) {
  __builtin_amdgcn_global_load_lds(
      (const __attribute__((address_space(1))) void*)g,
      (__attribute__((address_space(3))) void*)l, 16, 0, 0);
}

__device__ inline unsigned short f2bf(float f) {
  __bf16 h = (__bf16)f;
  return __builtin_bit_cast(unsigned short, h);
}

// ---------------------------------------------------------------------------
// Kernel A: [C][N] fp32 -> [N][C] bf16 + [N][C] fp32 (transpose + convert)
// ---------------------------------------------------------------------------
__global__ __launch_bounds__(256) void transpose_convert(
    const float* __restrict__ f1, const float* __restrict__ f2,
    __bf16* __restrict__ t1b, __bf16* __restrict__ t2b,
    float* __restrict__ t1f, float* __restrict__ t2f)
{
  __shared__ float tile[64][65];
  const int tid = threadIdx.x;
  const int bid = blockIdx.x;
  const int map = bid / 768;
  const int rem = bid % 768;
  const int b   = rem / 384;
  const int r2  = rem % 384;
  const int c0  = (r2 / 96) * 64;
  const int n0  = (r2 % 96) * 64;

  const float* src = (map ? f2 : f1) + (size_t)b*Cc*Nn;
  __bf16* dstb = (map ? t2b : t1b) + (size_t)b*Nn*Cc;
  float*  dstf = (map ? t2f : t1f) + (size_t)b*Nn*Cc;

  const int nl = tid & 63;
  const int cb = tid >> 6;
  #pragma unroll
  for (int i = 0; i < 16; ++i) {
    const int c = cb + i*4;
    tile[nl][c] = src[(size_t)(c0 + c)*Nn + n0 + nl];
  }
  __syncthreads();
  #pragma unroll
  for (int j = 0; j < 4; ++j) {
    const int idx = j*256 + tid;
    const int n = idx >> 4, c4 = idx & 15;
    float v0 = tile[n][c4*4+0], v1 = tile[n][c4*4+1];
    float v2 = tile[n][c4*4+2], v3 = tile[n][c4*4+3];
    const size_t obase = (size_t)(n0 + n)*Cc + c0 + c4*4;
    float4 vf = make_float4(v0, v1, v2, v3);
    *(float4*)(dstf + obase) = vf;
    ushort4 ub = make_ushort4(f2bf(v0), f2bf(v1), f2bf(v2), f2bf(v3));
    *(ushort4*)(dstb + obase) = ub;
  }
}

// ---------------------------------------------------------------------------
// Kernel B: bf16 MFMA correlation + packed-key per-thread top-6 prefilter.
// 1024 blocks x 256 thr (4 waves) = exactly 4 blocks/CU, one clean round.
// Tile: 48 f1-rows x 1536 f2-cols, K=256; 12 iters of 128 cols.
// LDS 40 KB: As 24K + Bs 2x8K double-buffer. Wave-private, no loop barriers.
// ---------------------------------------------------------------------------
__global__ __launch_bounds__(256, 4) void mfma_prefilter(
    const __bf16* __restrict__ f1t, const __bf16* __restrict__ f2t,
    unsigned* __restrict__ pv)
{
  __shared__ __align__(16) char smem[40960];
  // As: [0, 24576): 48 rows x 512 B, granule-swizzled
  // Bs[q]: 24576 + q*8192: 128 cols x 64 B
  unsigned* mk = (unsigned*)smem;        // merge keys [48][97] u32 (18.6 KB)

  const int tid  = threadIdx.x;
  const int lane = tid & 63;
  const int wv   = tid >> 6;
  const int bid  = blockIdx.x;
  const int b    = bid / (128*SCH);
  const int r2   = bid % (128*SCH);
  const int row0 = (r2 >> 2) * ROWT;     // 128 row-tiles of 48
  const int sc   = r2 & 3;
  const int col0 = sc * CPC;
  const size_t bN = (size_t)b * Nn;

  // ---- stage A (48 rows x 256 K, 24 KB): 24 segs of 1 KB, 6 per wave
  #pragma unroll
  for (int i = 0; i < 6; ++i) {
    const int seg = wv*6 + i;
    const int row = seg*2 + (lane >> 5);
    const int gs  = lane & 31;
    const __bf16* gp = f1t + ((bN + row0 + row) << 8) + ((gs ^ (row & 7)) << 3);
    gld16(gp, smem + seg*1024);
  }

  // ---- per-lane source offsets for B staging (wave quadrant: 32 cols/iter)
  // seg i covers iter-local cols [wv*32 + i*16, +16); lane: col=lane>>2, gran=lane&3
  size_t offB[2];
  #pragma unroll
  for (int i = 0; i < 2; ++i) {
    const int cl = wv*32 + i*16 + (lane >> 2);       // col within 128-col iter
    const int g2 = (lane & 3) ^ ((cl >> 1) & 3);     // pre-swizzled source granule
    offB[i] = ((bN + col0 + cl) << 8) + (g2 << 3);
  }
  // chunk kc of iter: source elems + iter*128*256 + kc*32
  #define STAGE_B(q, elemoff) do {                                        \
    _Pragma("unroll")                                                     \
    for (int _i = 0; _i < 2; ++_i)                                        \
      gld16(f2t + offB[_i] + (elemoff),                                   \
            smem + 24576 + (q)*8192 + wv*2048 + _i*1024);                 \
  } while (0)

  STAGE_B(0, 0);
  asm volatile("s_waitcnt vmcnt(2)" ::: "memory");   // A landed (B0 in flight)
  __builtin_amdgcn_sched_barrier(0);
  __syncthreads();

  // ---- hoist f1 fragments for kc<HOIST (iter-invariant)
  bf16x8 bfrH[3][HOIST];
  #pragma unroll
  for (int kc = 0; kc < HOIST; ++kc)
    #pragma unroll
    for (int cg = 0; cg < 3; ++cg) {
      const int rw = cg*16 + (lane & 15);
      const int gas = (kc*4 + (lane >> 4)) ^ (rw & 7);
      bfrH[cg][kc] = *(const bf16x8*)((const char*)smem + rw*512 + gas*16);
    }

  float va[3][TKEEP];
  #pragma unroll
  for (int cg = 0; cg < 3; ++cg)
    #pragma unroll
    for (int j = 0; j < TKEEP; ++j) va[cg][j] = KNEG;

  for (int iter = 0; iter < NITER; ++iter) {
    f32x4v acc[2][3];
    #pragma unroll
    for (int rg = 0; rg < 2; ++rg)
      #pragma unroll
      for (int cg = 0; cg < 3; ++cg)
        acc[rg][cg] = (f32x4v){0.f, 0.f, 0.f, 0.f};

    #pragma unroll
    for (int kc = 0; kc < 8; ++kc) {
      if (kc < 7) {
        STAGE_B((kc+1)&1, (size_t)iter*32768 + (kc+1)*32);
        asm volatile("s_waitcnt vmcnt(2)" ::: "memory");
      } else if (iter < NITER-1) {
        STAGE_B(0, (size_t)(iter+1)*32768);
        asm volatile("s_waitcnt vmcnt(2)" ::: "memory");
      } else {
        asm volatile("s_waitcnt vmcnt(0)" ::: "memory");
      }
      __builtin_amdgcn_sched_barrier(0);

      bf16x8 af[2], bfr[3];
      const int q = kc & 1;
      #pragma unroll
      for (int rg = 0; rg < 2; ++rg) {               // f2 cols (A-operand)
        const int cl = wv*32 + rg*16 + (lane & 15);
        const int gsw = (lane >> 4) ^ ((cl >> 1) & 3);
        af[rg] = *(const bf16x8*)(smem + 24576 + q*8192 + cl*64 + gsw*16);
      }
      #pragma unroll
      for (int cg = 0; cg < 3; ++cg) {               // f1 rows (B-operand)
        if (kc < HOIST) {
          bfr[cg] = bfrH[cg][kc];
        } else {
          const int rw = cg*16 + (lane & 15);
          const int gas = (kc*4 + (lane >> 4)) ^ (rw & 7);
          bfr[cg] = *(const bf16x8*)((const char*)smem + rw*512 + gas*16);
        }
      }
      __builtin_amdgcn_s_setprio(1);
      #pragma unroll
      for (int rg = 0; rg < 2; ++rg)
        #pragma unroll
        for (int cg = 0; cg < 3; ++cg)
          acc[rg][cg] = __builtin_amdgcn_mfma_f32_16x16x32_bf16(
              af[rg], bfr[cg], acc[rg][cg], 0, 0, 0);
      __builtin_amdgcn_s_setprio(0);
    }

    // packed-key top-6 update: D[f2col][f1row], one list per f1row (static cg)
    const int colB = col0 + iter*128 + wv*32 + ((lane >> 4) << 2);
    #pragma unroll
    for (int cg = 0; cg < 3; ++cg)
      #pragma unroll
      for (int rg = 0; rg < 2; ++rg)
        #pragma unroll
        for (int j = 0; j < 4; ++j) {
          const unsigned u =
              (__float_as_uint(acc[rg][cg][j]) & 0xFFFFE000u) |
              (unsigned)(colB + rg*16 + j);
          KEY_INS(__uint_as_float(u), va[cg], TKEEP);
        }
  }

  // ---- final merge: 16 thread-lists per row (96 keys) -> top-8 per row ----
  __syncthreads();
  const int slot = wv*4 + (lane >> 4);
  #pragma unroll
  for (int cg = 0; cg < 3; ++cg) {
    const int row = cg*16 + (lane & 15);
    #pragma unroll
    for (int j = 0; j < TKEEP; ++j)
      mk[row*97 + slot*TKEEP + j] = __float_as_uint(va[cg][j]);
  }
  __syncthreads();
  if (tid < ROWT) {
    float tv[8];
    #pragma unroll
    for (int j = 0; j < 8; ++j) tv[j] = KNEG;
    for (int e = 0; e < 16*TKEEP; ++e)
      KEY_INS(__uint_as_float(mk[tid*97 + e]), tv, 8);
    const size_t base = (bN + row0 + tid)*32 + sc*8;
    #pragma unroll
    for (int j = 0; j < 8; ++j) pv[base + j] = __float_as_uint(tv[j]);
  }
}

// ---------------------------------------------------------------------------
// Kernel C: 32 keys -> approx top-16 -> exact fp32 rescore -> exact top-8.
// 1536 blocks x 256 thr, 8 n each (2x TLP vs R6); f1 staged once in LDS.
// ---------------------------------------------------------------------------
__global__ __launch_bounds__(256) void rescore_select(
    const unsigned* __restrict__ pv,
    const float* __restrict__ t1f, const float* __restrict__ t2f,
    float* __restrict__ fv, int* __restrict__ fi)
{
  __shared__ float f1s[8][256];    // 8 KB
  __shared__ int   cidx[8][16];
  __shared__ float cex[8][16];

  const int tid = threadIdx.x;
  const int bid = blockIdx.x;
  const int b   = bid / 768;
  const int n0  = (bid % 768) * 8;
  const size_t bn0 = (size_t)b*Nn + n0;

  // stage f1 rows: 8 x 1 KB
  #pragma unroll
  for (int k = 0; k < 2; ++k) {
    const int idx = k*256 + tid;
    const int r = idx >> 6, p = idx & 63;
    *(float4*)(&f1s[r][p*4]) = *(const float4*)(t1f + (bn0 + r)*256 + p*4);
  }

  // phase 1: one thread per n: key-ladder top-16 of 32
  if (tid < 8) {
    float va[16];
    #pragma unroll
    for (int j = 0; j < 16; ++j) va[j] = KNEG;
    const size_t base = (bn0 + tid)*32;
    for (int e = 0; e < 32; ++e)
      KEY_INS(__uint_as_float(pv[base + e]), va, 16);
    #pragma unroll
    for (int j = 0; j < 16; ++j)
      cidx[tid][j] = (int)(__float_as_uint(va[j]) & 0x1FFFu);
  }
  __syncthreads();

  // phase 2: exact fp32 rescore: wave handles 2 n; 8 lanes per candidate
  {
    const int lane = tid & 63;
    const int cg = lane >> 3, li = lane & 7;
    #pragma unroll
    for (int nn = 0; nn < 2; ++nn) {
      const int nl = (tid >> 6)*2 + nn;
      #pragma unroll
      for (int p = 0; p < 2; ++p) {
        const int cand = p*8 + cg;
        const int m = cidx[nl][cand];
        const float4* p2 = (const float4*)(t2f + ((size_t)b*Nn + m)*256);
        float sum = 0.f;
        #pragma unroll
        for (int j = 0; j < 8; ++j) {
          const int fi4 = j*8 + li;
          float4 a = *(const float4*)(&f1s[nl][fi4*4]);
          float4 c = p2[fi4];
          sum += a.x*c.x + a.y*c.y + a.z*c.z + a.w*c.w;
        }
        sum += __shfl_xor(sum, 1);
        sum += __shfl_xor(sum, 2);
        sum += __shfl_xor(sum, 4);
        if (li == 0) cex[nl][cand] = sum;
      }
    }
  }
  __syncthreads();

  // phase 3: exact top-8 of 16, write final
  if (tid < 8) {
    float va[8]; int ia[8];
    #pragma unroll
    for (int j = 0; j < 8; ++j) { va[j] = -INFINITY; ia[j] = 0; }
    #pragma unroll
    for (int e = 0; e < 16; ++e)
      TOPK_INS(cex[tid][e], cidx[tid][e], va, ia, 8);
    const size_t base = (bn0 + tid)*8;
    #pragma unroll
    for (int j = 0; j < 8; ++j) { fv[base+j] = va[j]; fi[base+j] = ia[j]; }
  }
}

// ---------------------------------------------------------------------------
// Kernel D: displacement -> 5-level bilinear scatter
// ---------------------------------------------------------------------------
__global__ __launch_bounds__(128) void pyramid_kernel(
    const float* __restrict__ fv, const int* __restrict__ fi,
    const float* __restrict__ flow, float* __restrict__ out)
{
  __shared__ float accs[128*81];
  const int tid = threadIdx.x;
  const int g   = blockIdx.x*128 + tid;   // b*N + n
  const int lvl = blockIdx.y;
  const int b   = g / Nn;
  const int n   = g % Nn;

  float tvv[8]; int ti[8];
  #pragma unroll
  for (int k = 0; k < 8; ++k) { tvv[k] = fv[(size_t)g*8 + k]; ti[k] = fi[(size_t)g*8 + k]; }

  const int y = n / Ww, x = n % Ww;
  const float fly = flow[((size_t)b*2 + 1)*Nn + n];
  const float flx = flow[((size_t)b*2 + 0)*Nn + n];
  const float scale = 1.0f / (float)(1 << lvl);

  float* lacc = &accs[tid*81];
  #pragma unroll
  for (int c2 = 0; c2 < 81; ++c2) lacc[c2] = 0.f;

  #pragma unroll
  for (int k = 0; k < 8; ++k) {
    const int m  = ti[k];
    const int ym = m / Ww, xm = m % Ww;
    const float val = tvv[k] * 0.0625f;
    const float cy = ((float)(ym - y) - fly) * scale;
    const float cx = ((float)(xm - x) - flx) * scale;
    const float fy0 = floorf(cy), fx0 = floorf(cx);
    const float ry = cy - fy0, rx = cx - fx0;
    const int iy = (int)fy0, ix = (int)fx0;
    if (iy   >= -4 && iy   <= 4 && ix   >= -4 && ix   <= 4)
      lacc[(iy+4)*9 + (ix+4)]     += (1.f-ry)*(1.f-rx)*val;
    if (iy   >= -4 && iy   <= 4 && ix+1 >= -4 && ix+1 <= 4)
      lacc[(iy+4)*9 + (ix+1+4)]   += (1.f-ry)*rx*val;
    if (iy+1 >= -4 && iy+1 <= 4 && ix   >= -4 && ix   <= 4)
      lacc[(iy+1+4)*9 + (ix+4)]   += ry*(1.f-rx)*val;
    if (iy+1 >= -4 && iy+1 <= 4 && ix+1 >= -4 && ix+1 <= 4)
      lacc[(iy+1+4)*9 + (ix+1+4)] += ry*rx*val;
  }

  const size_t obase = ((size_t)b*(NLEV*81) + lvl*81) * Nn + n;
  #pragma unroll
  for (int c2 = 0; c2 < 81; ++c2)
    out[obase + (size_t)c2*Nn] = lacc[c2];
}

// ---------------------------------------------------------------------------
extern "C" void kernel_launch(void* const* d_in, const int* in_sizes, int n_in,
                              void* d_out, int out_size, void* d_ws, size_t ws_size,
                              hipStream_t stream) {
  const float* fmap1 = (const float*)d_in[0];
  const float* fmap2 = (const float*)d_in[1];
  const float* flow  = (const float*)d_in[2];
  float* out = (float*)d_out;

  char* w = (char*)d_ws;
  const size_t szBf  = (size_t)Bn*Nn*Cc*sizeof(unsigned short); // 6.29 MB
  const size_t szF   = (size_t)Bn*Nn*Cc*sizeof(float);          // 12.58 MB
  const size_t szPv  = (size_t)Bn*Nn*32*sizeof(unsigned);       // 1.57 MB
  const size_t szFv  = (size_t)Bn*Nn*8*sizeof(float);           // 0.39 MB

  __bf16*   t1b = (__bf16*)(w);
  __bf16*   t2b = (__bf16*)(w + szBf);
  float*    t1f = (float*)(w + 2*szBf);
  float*    t2f = (float*)(w + 2*szBf + szF);
  unsigned* pv  = (unsigned*)(w + 2*szBf + 2*szF);
  float*    fv  = (float*)(w + 2*szBf + 2*szF + szPv);
  int*      fi  = (int*)  (w + 2*szBf + 2*szF + szPv + szFv);

  transpose_convert<<<dim3(1536), dim3(256), 0, stream>>>(fmap1, fmap2, t1b, t2b, t1f, t2f);
  mfma_prefilter  <<<dim3(Bn*128*SCH), dim3(256), 0, stream>>>(t1b, t2b, pv);
  rescore_select  <<<dim3(1536), dim3(256), 0, stream>>>(pv, t1f, t2f, fv, fi);
  pyramid_kernel  <<<dim3(96, NLEV), dim3(128), 0, stream>>>(fv, fi, flow, out);
}